// Round 4
// baseline (283.798 us; speedup 1.0000x reference)
//
#include <hip/hip_runtime.h>
#include <math.h>

#define N_ 4096

// ---------------- workspace float offsets -----------------------------------
static constexpr size_t OFF_HP0    = 2048;     // [16][4096][32]; ELU aliases
static constexpr size_t OFF_ELU    = 2048;     // [4][4096][128]
static constexpr size_t OFF_SS0    = 2099200;
static constexpr size_t OFF_SD0    = 2164736;
static constexpr size_t OFF_SV0    = 2361344;
static constexpr size_t OFF_PM0    = 2426880;
static constexpr size_t OFF_EP0    = 2492416;
static constexpr size_t OFF_EN0    = 2557952;
static constexpr size_t OFF_CPP0   = 2623488;  // [16][4097] scalar count prefixes
static constexpr size_t OFF_CPN0   = 2689040;
static constexpr size_t OFF_RAWP0  = 2754592;  // [16][256][32]
static constexpr size_t OFF_RAWN0  = 2885664;
static constexpr size_t OFF_BP0    = 3016736;  // [16][257][32]
static constexpr size_t OFF_BN0    = 3148320;
static constexpr size_t OFF_TPP0   = 3279904;  // [16][4097][32]
static constexpr size_t OFF_TPN0   = 5377568;  // ends 7475232
// ---- layer1 aliases TPP0/TPN0 region (dead after keval0) ----
static constexpr size_t OFF_HP1    = 3279904;  // [4][4096][64]
static constexpr size_t OFF_SS1    = 4328480;
static constexpr size_t OFF_SD1    = 4344864;
static constexpr size_t OFF_SV1    = 4394016;
static constexpr size_t OFF_PM1    = 4410400;
static constexpr size_t OFF_EP1    = 4426784;
static constexpr size_t OFF_EN1    = 4443168;
static constexpr size_t OFF_CPP1   = 4459552;  // [4][4097]
static constexpr size_t OFF_CPN1   = 4475940;
static constexpr size_t OFF_RAWP1  = 4492328;  // [4][256][64]
static constexpr size_t OFF_RAWN1  = 4557864;
static constexpr size_t OFF_BP1    = 4623400;  // [4][257][64]
static constexpr size_t OFF_BN1    = 4689192;
static constexpr size_t OFF_TPP1   = 4754984;  // [4][4097][64]
static constexpr size_t OFF_TPN1   = 5803816;  // ends 6852648
// ---- stats partials/accumulator: MUST live past TPN0 end (7475232)! --------
// (round-3 bug: ACC1 inside TPN0 range was clobbered by ktables0 between
//  kstats' zeroing and keval0's atomic accumulation)
static constexpr size_t OFF_S0P    = 7475232;  // [4][32][64][2]  = 16384
static constexpr size_t OFF_ACC1   = 7491616;  // [4][128][2]     = 1024; end 7492640 ~30 MB

__device__ __forceinline__ unsigned f2s(float f){
  unsigned u=__float_as_uint(f);
  return u^((u&0x80000000u)?0xFFFFFFFFu:0x80000000u);
}
__device__ __forceinline__ float s2f(unsigned s){
  unsigned u=(s&0x80000000u)?(s^0x80000000u):~s;
  return __uint_as_float(u);
}
__device__ __forceinline__ void fma4(float4& a, float s, float4 w){
  a.x+=s*w.x; a.y+=s*w.y; a.z+=s*w.z; a.w+=s*w.w;
}
__device__ __forceinline__ float dot4(float4 a, float4 b){
  return a.x*b.x+a.y*b.y+a.z*b.z+a.w*b.w;
}

// ---------- layer0 partial stats (coalesced) + zero layer1 accumulator -------
template<int C>
__global__ void kstats(const float* __restrict__ x, float* __restrict__ statsP,
                       float* __restrict__ acc1){
  int blk=blockIdx.x; int b=blk>>5;
  int tid=threadIdx.x;
  if(blk==0){ ((float4*)acc1)[tid]=make_float4(0.f,0.f,0.f,0.f); }  // 1024 floats
  const int RPT=256/C;
  const int IT=128/RPT;
  int c=tid%C, rl=tid/C;
  const float* xb=x+(size_t)b*N_*C;
  float s1=0.f,s2=0.f;
  int r0=(blk&31)*128+rl;
  for(int i=0;i<IT;i++){
    float v=xb[(size_t)(r0+i*RPT)*C+c];
    s1+=v;s2+=v*v;
  }
  __shared__ float sh1[256],sh2[256];
  sh1[tid]=s1;sh2[tid]=s2;__syncthreads();
  if(tid<C){
    float a1=0.f,a2=0.f;
    for(int g=0;g<RPT;g++){a1+=sh1[g*C+tid];a2+=sh2[g*C+tid];}
    statsP[((size_t)blk*C+tid)*2+0]=a1;
    statsP[((size_t)blk*C+tid)*2+1]=a2;
  }
}

// ---------- layer0 projection: R=4 rows/lane, 8 cols/wave --------------------
__global__ void __launch_bounds__(256) kproj0(
                       const float* __restrict__ x, const float* __restrict__ statsP,
                       const float* __restrict__ w0, const float* __restrict__ asrc,
                       const float* __restrict__ adst, float* __restrict__ hp,
                       float* __restrict__ ss, float* __restrict__ sd){
  __shared__ float4 w4[512];            // [64 d][8 q] head-h slice (8 KB)
  __shared__ float mean[64],rstd[64];
  __shared__ float red1[256],red2[256];
  __shared__ float ssP[1024],sdP[1024]; // [4 wave][256 rowslot]
  int tid=threadIdx.x;
  int blk=blockIdx.x;
  int b=blk>>6, h=(blk>>4)&3, nb=blk&15;
  const float4* wg=(const float4*)w0+(size_t)h*512;
  w4[tid]=wg[tid]; w4[tid+256]=wg[tid+256];
  {
    int tc=tid&63, tg=tid>>6;
    float a1=0.f,a2=0.f;
    #pragma unroll 2
    for(int g=tg*8;g<tg*8+8;g++){
      a1+=statsP[((size_t)(b*32+g)*64+tc)*2+0];
      a2+=statsP[((size_t)(b*32+g)*64+tc)*2+1];
    }
    red1[tid]=a1; red2[tid]=a2;
  }
  __syncthreads();
  if(tid<64){
    float s1=red1[tid]+red1[tid+64]+red1[tid+128]+red1[tid+192];
    float s2=red2[tid]+red2[tid+64]+red2[tid+128]+red2[tid+192];
    float mu=s1*(1.0f/N_);
    float var=s2*(1.0f/N_)-mu*mu;
    mean[tid]=mu; rstd[tid]=rsqrtf(var+1e-5f);
  }
  __syncthreads();
  int w=tid>>6, lane=tid&63;
  int n0=nb*256+lane;
  const float4* xb=(const float4*)(x+((size_t)b*N_+n0)*64);
  float4 acc[4][2];
  #pragma unroll
  for(int r=0;r<4;r++){acc[r][0]=make_float4(0,0,0,0);acc[r][1]=make_float4(0,0,0,0);}
  for(int ch=0;ch<8;ch++){
    float4 wr[8][2];
    #pragma unroll
    for(int dd=0;dd<8;dd++){
      wr[dd][0]=w4[(ch*8+dd)*8+w*2+0];
      wr[dd][1]=w4[(ch*8+dd)*8+w*2+1];
    }
    float4 mn0=*(const float4*)&mean[ch*8], mn1=*(const float4*)&mean[ch*8+4];
    float4 rs0=*(const float4*)&rstd[ch*8], rs1=*(const float4*)&rstd[ch*8+4];
    #pragma unroll
    for(int r=0;r<4;r++){
      float4 t0=xb[(size_t)r*1024+ch*2+0];
      float4 t1=xb[(size_t)r*1024+ch*2+1];
      float hv[8];
      hv[0]=(t0.x-mn0.x)*rs0.x; hv[1]=(t0.y-mn0.y)*rs0.y;
      hv[2]=(t0.z-mn0.z)*rs0.z; hv[3]=(t0.w-mn0.w)*rs0.w;
      hv[4]=(t1.x-mn1.x)*rs1.x; hv[5]=(t1.y-mn1.y)*rs1.y;
      hv[6]=(t1.z-mn1.z)*rs1.z; hv[7]=(t1.w-mn1.w)*rs1.w;
      #pragma unroll
      for(int dd=0;dd<8;dd++){
        fma4(acc[r][0],hv[dd],wr[dd][0]);
        fma4(acc[r][1],hv[dd],wr[dd][1]);
      }
    }
  }
  float4 a1v0=((const float4*)asrc)[h*8+w*2+0];
  float4 a1v1=((const float4*)asrc)[h*8+w*2+1];
  float4 a2v0=((const float4*)adst)[h*8+w*2+0];
  float4 a2v1=((const float4*)adst)[h*8+w*2+1];
  int p=b*4+h;
  #pragma unroll
  for(int r=0;r<4;r++){
    ssP[w*256+r*64+lane]=dot4(acc[r][0],a1v0)+dot4(acc[r][1],a1v1);
    sdP[w*256+r*64+lane]=dot4(acc[r][0],a2v0)+dot4(acc[r][1],a2v1);
    float4* o4=(float4*)(hp+((size_t)p*N_+n0+r*64)*32+w*8);
    o4[0]=acc[r][0]; o4[1]=acc[r][1];
  }
  __syncthreads();
  {
    float s=ssP[tid]+ssP[256+tid]+ssP[512+tid]+ssP[768+tid];
    float d=sdP[tid]+sdP[256+tid]+sdP[512+tid]+sdP[768+tid];
    ss[(size_t)p*N_+nb*256+tid]=s;
    sd[(size_t)p*N_+nb*256+tid]=d;
  }
}

// ---------- layer1 projection: stats from atomic accumulator -----------------
__global__ void __launch_bounds__(256) kproj1(
                       const float* __restrict__ x, const float* __restrict__ acc1,
                       const float* __restrict__ w1, const float* __restrict__ asrc,
                       const float* __restrict__ adst, float* __restrict__ hp,
                       float* __restrict__ ss, float* __restrict__ sd){
  __shared__ float4 w4[512];            // [128 d][4 c] col-slice of cgq (8 KB)
  __shared__ float wa[128],wd[128],mean[128],rstd[128];
  int tid=threadIdx.x;
  int blk=blockIdx.x;
  int b=blk>>6, cgq=(blk>>4)&3, nb=blk&15;
  {
    const float4* wg=(const float4*)w1;
    int i=tid;       int d=i>>2, c=i&3; w4[i]=wg[d*16+cgq*4+c];
    i=tid+256;       d=i>>2;     c=i&3; w4[i]=wg[d*16+cgq*4+c];
  }
  if(tid<128){
    float s1a=0.f,s2a=0.f;
    for(int k=0;k<64;k++){float wv=w1[tid*64+k];s1a+=wv*asrc[k];s2a+=wv*adst[k];}
    wa[tid]=s1a;wd[tid]=s2a;
    float s1=acc1[((size_t)b*128+tid)*2+0];
    float s2=acc1[((size_t)b*128+tid)*2+1];
    float mu=s1*(1.0f/N_);
    float var=s2*(1.0f/N_)-mu*mu;
    mean[tid]=mu; rstd[tid]=rsqrtf(var+1e-5f);
  }
  __syncthreads();
  int w=tid>>6, lane=tid&63;
  int cg=cgq*4+w;
  int n0=nb*256+lane;
  const float4* xb=(const float4*)(x+((size_t)b*N_+n0)*128);
  float4 acc[4];
  #pragma unroll
  for(int r=0;r<4;r++) acc[r]=make_float4(0,0,0,0);
  float s1a[4]={0.f,0.f,0.f,0.f}, s2a[4]={0.f,0.f,0.f,0.f};
  bool dosum=(cgq==0)&&(w==0);
  for(int ch=0;ch<16;ch++){
    float4 wr[8];
    #pragma unroll
    for(int dd=0;dd<8;dd++) wr[dd]=w4[(ch*8+dd)*4+w];
    float4 mn0=*(const float4*)&mean[ch*8], mn1=*(const float4*)&mean[ch*8+4];
    float4 rs0=*(const float4*)&rstd[ch*8], rs1=*(const float4*)&rstd[ch*8+4];
    float4 wa0,wa1,wd0,wd1;
    if(dosum){
      wa0=*(const float4*)&wa[ch*8]; wa1=*(const float4*)&wa[ch*8+4];
      wd0=*(const float4*)&wd[ch*8]; wd1=*(const float4*)&wd[ch*8+4];
    }
    #pragma unroll
    for(int r=0;r<4;r++){
      float4 t0=xb[(size_t)r*2048+ch*2+0];
      float4 t1=xb[(size_t)r*2048+ch*2+1];
      float hv[8];
      hv[0]=(t0.x-mn0.x)*rs0.x; hv[1]=(t0.y-mn0.y)*rs0.y;
      hv[2]=(t0.z-mn0.z)*rs0.z; hv[3]=(t0.w-mn0.w)*rs0.w;
      hv[4]=(t1.x-mn1.x)*rs1.x; hv[5]=(t1.y-mn1.y)*rs1.y;
      hv[6]=(t1.z-mn1.z)*rs1.z; hv[7]=(t1.w-mn1.w)*rs1.w;
      #pragma unroll
      for(int dd=0;dd<8;dd++) fma4(acc[r],hv[dd],wr[dd]);
      if(dosum){
        s1a[r]+=hv[0]*wa0.x+hv[1]*wa0.y+hv[2]*wa0.z+hv[3]*wa0.w
               +hv[4]*wa1.x+hv[5]*wa1.y+hv[6]*wa1.z+hv[7]*wa1.w;
        s2a[r]+=hv[0]*wd0.x+hv[1]*wd0.y+hv[2]*wd0.z+hv[3]*wd0.w
               +hv[4]*wd1.x+hv[5]*wd1.y+hv[6]*wd1.z+hv[7]*wd1.w;
      }
    }
  }
  #pragma unroll
  for(int r=0;r<4;r++){
    float4* o4=(float4*)(hp+((size_t)b*N_+n0+r*64)*64+cg*4);
    o4[0]=acc[r];
  }
  if(dosum){
    #pragma unroll
    for(int r=0;r<4;r++){
      ss[(size_t)b*N_+n0+r*64]=s1a[r];
      sd[(size_t)b*N_+n0+r*64]=s2a[r];
    }
  }
}

// ---------- fused sort(4x1024 bitonic) + merge-by-rank, one block per p ------
__global__ void __launch_bounds__(1024) ksortmerge(const float* __restrict__ sdst,
    float* __restrict__ sv, unsigned* __restrict__ perm,
    float* __restrict__ eP, float* __restrict__ eN){
  __shared__ unsigned long long sm[4096];   // 32 KB
  int p=blockIdx.x, tid=threadIdx.x;
  const float* s=sdst+(size_t)p*N_;
  for(int l=tid;l<4096;l+=1024){
    unsigned key=f2s(s[l]);
    sm[l]=((unsigned long long)key<<32)|(unsigned)l;
  }
  // 4 independent 1024-sorts in parallel (16 waves, lockstep barriers)
  int run=tid>>8; unsigned tt=(unsigned)(tid&255);
  unsigned long long* base=sm+((size_t)run<<10);
  for(unsigned k=2;k<=1024u;k<<=1)
    for(unsigned j=k>>1;j>0;j>>=1){
      __syncthreads();
      for(unsigned t=tt;t<512u;t+=256u){
        unsigned i=((t&~(j-1))<<1)|(t&(j-1));
        unsigned q=i|j;
        bool up=((i&k)==0);
        unsigned long long a=base[i],b=base[q];
        if((a>b)==up){base[i]=b;base[q]=a;}
      }
    }
  __syncthreads();
  unsigned long long mk=sm[1023];
  if(sm[2047]>mk)mk=sm[2047];
  if(sm[3071]>mk)mk=sm[3071];
  if(sm[4095]>mk)mk=sm[4095];
  float m=s2f((unsigned)(mk>>32));
  // merge: each thread ranks one element per run
  #pragma unroll
  for(int cg=0;cg<4;cg++){
    unsigned long long e=sm[(cg<<10)+tid];
    int rank=tid;
    #pragma unroll
    for(int o=0;o<4;o++){
      if(o==cg) continue;
      const unsigned long long* ob=sm+((size_t)o<<10);
      int lo=0,hi=1024;
      while(lo<hi){int mid=(lo+hi)>>1; if(ob[mid]<e) lo=mid+1; else hi=mid;}
      rank+=lo;
    }
    float v=s2f((unsigned)(e>>32));
    size_t o2=(size_t)p*N_+rank;
    sv[o2]=v;
    perm[o2]=(unsigned)(e&0xffffffffu);
    eP[o2]=expf(v-m);
    eN[o2]=expf(0.2f*(v-m));
  }
}

// ---------- counts role-block: absolute scalar count prefixes for one p ------
__device__ __forceinline__ void counts_block(const float* __restrict__ eP,
    const float* __restrict__ eN, float* __restrict__ CPP, float* __restrict__ CPN,
    int p, float* s){
  int t=threadIdx.x;
  for(int pass=0;pass<2;pass++){
    const float* e=pass?eN:eP;
    float* C=pass?CPN:CPP;
    const float4* e4=(const float4*)(e+(size_t)p*N_);
    float4 a0=e4[t*4+0],a1=e4[t*4+1],a2=e4[t*4+2],a3=e4[t*4+3];
    float lp=a0.x+a0.y+a0.z+a0.w+a1.x+a1.y+a1.z+a1.w
            +a2.x+a2.y+a2.z+a2.w+a3.x+a3.y+a3.z+a3.w;
    if(pass) __syncthreads();
    s[t]=lp; __syncthreads();
    for(int off=1;off<256;off<<=1){
      float tv=(t>=off)?s[t-off]:0.f;
      __syncthreads();
      s[t]+=tv;
      __syncthreads();
    }
    float bp=s[t]-lp;
    size_t o=(size_t)p*4097+(size_t)t*16;
    C[o+ 0]=bp; bp+=a0.x; C[o+ 1]=bp; bp+=a0.y; C[o+ 2]=bp; bp+=a0.z; C[o+ 3]=bp; bp+=a0.w;
    C[o+ 4]=bp; bp+=a1.x; C[o+ 5]=bp; bp+=a1.y; C[o+ 6]=bp; bp+=a1.z; C[o+ 7]=bp; bp+=a1.w;
    C[o+ 8]=bp; bp+=a2.x; C[o+ 9]=bp; bp+=a2.y; C[o+10]=bp; bp+=a2.z; C[o+11]=bp; bp+=a2.w;
    C[o+12]=bp; bp+=a3.x; C[o+13]=bp; bp+=a3.y; C[o+14]=bp; bp+=a3.z; C[o+15]=bp;
    if(t==255) C[(size_t)p*4097+4096]=s[255];
  }
}

// ---------- layer0 relative tables + fused counts (blocks 0..15) -------------
__global__ void __launch_bounds__(256) ktables0(const unsigned* __restrict__ perm,
    const float* __restrict__ eP, const float* __restrict__ eN,
    const float* __restrict__ hp, float* __restrict__ TPP, float* __restrict__ TPN,
    float* __restrict__ rawP, float* __restrict__ rawN,
    float* __restrict__ CPP, float* __restrict__ CPN){
  __shared__ float s[256];
  if(blockIdx.x<16){ counts_block(eP,eN,CPP,CPN,blockIdx.x,s); return; }
  int gw=((blockIdx.x-16)*256+threadIdx.x)>>6;   // 0..2047
  int lane=threadIdx.x&63, half=lane>>5, ch=lane&31;
  int cglob=gw*2+half;
  int p=cglob>>8, c=cglob&255;
  float aP=0.f,aN=0.f;
  for(int q=0;q<16;q++){
    int r=c*16+q;
    size_t ro=(size_t)p*N_+r;
    float ep=eP[ro],en=eN[ro];
    unsigned pr=perm[ro];
    float hv=hp[((size_t)p*N_+pr)*32+ch];
    size_t to=((size_t)p*4097+r)*32+ch;
    TPP[to]=aP; TPN[to]=aN;
    aP+=ep*hv; aN+=en*hv;
  }
  size_t bo=((size_t)p*256+c)*32+ch;
  rawP[bo]=aP; rawN[bo]=aN;
}

// ---------- layer1 relative tables + fused counts (blocks 0..3) --------------
__global__ void __launch_bounds__(256) ktables1(const unsigned* __restrict__ perm,
    const float* __restrict__ eP, const float* __restrict__ eN,
    const float* __restrict__ hp, float* __restrict__ TPP, float* __restrict__ TPN,
    float* __restrict__ rawP, float* __restrict__ rawN,
    float* __restrict__ CPP, float* __restrict__ CPN){
  __shared__ float s[256];
  if(blockIdx.x<4){ counts_block(eP,eN,CPP,CPN,blockIdx.x,s); return; }
  int wid=((blockIdx.x-4)*256+threadIdx.x)>>6;   // 0..1023
  int lane=threadIdx.x&63;
  int p=wid>>8, c=wid&255;
  float aP=0.f,aN=0.f;
  for(int q=0;q<16;q++){
    int r=c*16+q;
    size_t ro=(size_t)p*N_+r;
    float ep=eP[ro],en=eN[ro];
    unsigned pr=perm[ro];
    float hv=hp[((size_t)p*N_+pr)*64+lane];
    size_t to=((size_t)p*4097+r)*64+lane;
    TPP[to]=aP; TPN[to]=aN;
    aP+=ep*hv; aN+=en*hv;
  }
  size_t bo=((size_t)p*256+c)*64+lane;
  rawP[bo]=aP; rawN[bo]=aN;
}

// ---------- scan chunk sums -> bases; totals -> table row 4096 ---------------
template<int D>
__global__ void __launch_bounds__(256) kscan(const float* __restrict__ rawP,
    const float* __restrict__ rawN, float* __restrict__ bP, float* __restrict__ bN,
    float* __restrict__ TPP, float* __restrict__ TPN){
  __shared__ float ssum[256];
  int p=blockIdx.x>>1, pass=blockIdx.x&1;
  const float* src=pass?rawN:rawP;
  float* dst=pass?bN:bP;
  float* tp=pass?TPN:TPP;
  int tid=threadIdx.x;
  constexpr int SEG=256/D;
  int ch=tid&(D-1), sg=tid/D;
  const float* s0=src+(size_t)p*256*D;
  float acc=0.f;
  for(int c=sg*D;c<sg*D+D;c++) acc+=s0[c*D+ch];
  ssum[tid]=acc; __syncthreads();
  float base=0.f, tot=0.f;
  #pragma unroll
  for(int g=0;g<SEG;g++){float v=ssum[g*D+ch]; tot+=v; if(g<sg) base+=v;}
  float r=base;
  for(int c=sg*D;c<sg*D+D;c++){
    dst[((size_t)p*257+c)*D+ch]=r;
    r+=s0[c*D+ch];
  }
  if(sg==0){
    dst[((size_t)p*257+256)*D+ch]=0.f;
    tp[((size_t)p*4097+4096)*D+ch]=tot;
  }
}

// ---------- layer0 row eval + fused layer1 stats (atomic accumulator) --------
__global__ void __launch_bounds__(256) keval0(const float* __restrict__ ss,
                       const float* __restrict__ sv,
                       const float* __restrict__ bP, const float* __restrict__ bN,
                       const float* __restrict__ TPP, const float* __restrict__ TPN,
                       const float* __restrict__ CPP, const float* __restrict__ CPN,
                       const float* __restrict__ bias, float* __restrict__ out,
                       float* __restrict__ acc1){
  __shared__ float sm1[256],sm2[256];
  int tid=threadIdx.x;
  int gw=(blockIdx.x*256+tid)>>6;   // 0..32767
  int lane=tid&63, half=lane>>5, ch=lane&31;
  int row=gw*2+half;
  int p=row>>12, i=row&4095;
  int b=p>>2, h=p&3;
  const float* svp=sv+(size_t)p*N_;
  float ssrc=ss[(size_t)p*N_+i];
  float m=svp[4095];
  float xx=ssrc+m;
  float M=xx>0.f?xx:0.2f*xx;
  float fpos=expf(xx-M),fneg=expf(0.2f*xx-M);
  float th=-ssrc;
  float s1v=svp[ch*128+127];
  unsigned long long bal=__ballot(s1v<=th);
  int c1=half?(int)__popcll(bal>>32):(int)__popcll(bal&0xFFFFFFFFull);
  int lo;
  if(c1>=32){ lo=4096; }
  else{
    float s2v=svp[c1*128+ch*4+3];
    unsigned long long bal2=__ballot(s2v<=th);
    int c2=half?(int)__popcll(bal2>>32):(int)__popcll(bal2&0xFFFFFFFFull);
    int base=c1*128+c2*4;
    float4 qv=*((const float4*)(svp+base));
    int c3=(qv.x<=th)+(qv.y<=th)+(qv.z<=th)+(qv.w<=th);
    lo=base+c3;
  }
  int c=lo>>4;
  float relP=TPP[((size_t)p*4097+lo)*32+ch];
  float relN=TPN[((size_t)p*4097+lo)*32+ch];
  float baP=bP[((size_t)p*257+c)*32+ch];
  float baN=bN[((size_t)p*257+c)*32+ch];
  float tot=TPP[((size_t)p*4097+4096)*32+ch];
  float CPl=CPP[(size_t)p*4097+lo];
  float CNl=CPN[(size_t)p*4097+lo];
  float CT =CPP[(size_t)p*4097+4096];
  float denom=fpos*(CT-CPl)+fneg*CNl;
  float v=fpos*(tot-(baP+relP))+fneg*(baN+relN);
  float r=v/denom+bias[ch];
  r=r>0.f?r:expm1f(r);
  out[((size_t)(b*N_+i))*128+h*32+ch]=r;
  // ---- fused layer1 instance-norm partial stats: block covers 8 rows of (b,h)
  sm1[tid]=r; sm2[tid]=r*r;
  __syncthreads();
  if(tid<64){
    float a=sm1[tid]+sm1[tid+64]+sm1[tid+128]+sm1[tid+192];
    float q2=sm2[tid]+sm2[tid+64]+sm2[tid+128]+sm2[tid+192];
    sm1[tid]=a; sm2[tid]=q2;
  }
  __syncthreads();
  if(tid<32){
    float a=sm1[tid]+sm1[tid+32];
    float q2=sm2[tid]+sm2[tid+32];
    atomicAdd(&acc1[((size_t)b*128+h*32+tid)*2+0],a);
    atomicAdd(&acc1[((size_t)b*128+h*32+tid)*2+1],q2);
  }
}

// ---------- layer1 row eval: wave per row, width-64 --------------------------
__global__ void __launch_bounds__(256) keval1(const float* __restrict__ ss,
                       const float* __restrict__ sv,
                       const float* __restrict__ bP, const float* __restrict__ bN,
                       const float* __restrict__ TPP, const float* __restrict__ TPN,
                       const float* __restrict__ CPP, const float* __restrict__ CPN,
                       const float* __restrict__ bias, float* __restrict__ out){
  int wid=(blockIdx.x*256+threadIdx.x)>>6;   // p*4096+i
  int lane=threadIdx.x&63;
  int p=wid>>12, i=wid&4095;
  const float* svp=sv+(size_t)p*N_;
  float ssrc=ss[(size_t)p*N_+i];
  float m=svp[4095];
  float xx=ssrc+m;
  float M=xx>0.f?xx:0.2f*xx;
  float fpos=expf(xx-M),fneg=expf(0.2f*xx-M);
  float th=-ssrc;
  float s1v=svp[lane*64+63];
  int c1=(int)__popcll(__ballot(s1v<=th));
  int lo;
  if(c1>=64){ lo=4096; }
  else{
    float s2v=svp[c1*64+lane];
    lo=c1*64+(int)__popcll(__ballot(s2v<=th));
  }
  int c=lo>>4;
  float relP=TPP[((size_t)p*4097+lo)*64+lane];
  float relN=TPN[((size_t)p*4097+lo)*64+lane];
  float baP=bP[((size_t)p*257+c)*64+lane];
  float baN=bN[((size_t)p*257+c)*64+lane];
  float tot=TPP[((size_t)p*4097+4096)*64+lane];
  float CPl=CPP[(size_t)p*4097+lo];
  float CNl=CPN[(size_t)p*4097+lo];
  float CT =CPP[(size_t)p*4097+4096];
  float denom=fpos*(CT-CPl)+fneg*CNl;
  float v=fpos*(tot-(baP+relP))+fneg*(baN+relN);
  out[((size_t)p*N_+i)*64+lane]=v/denom+bias[lane];
}

extern "C" void kernel_launch(void* const* d_in, const int* in_sizes, int n_in,
                              void* d_out, int out_size, void* d_ws, size_t ws_size,
                              hipStream_t stream) {
  const float* x  =(const float*)d_in[0];
  const float* w0 =(const float*)d_in[1];
  const float* as0=(const float*)d_in[2];
  const float* ad0=(const float*)d_in[3];
  const float* b0 =(const float*)d_in[4];
  const float* w1 =(const float*)d_in[5];
  const float* as1=(const float*)d_in[6];
  const float* ad1=(const float*)d_in[7];
  const float* b1 =(const float*)d_in[8];
  float* ws=(float*)d_ws;
  float* out=(float*)d_out;

  float* s0p = ws+OFF_S0P;
  float* acc1= ws+OFF_ACC1;
  float* hp0 = ws+OFF_HP0;
  float* elu = ws+OFF_ELU;
  float* ss0 = ws+OFF_SS0;  float* sd0 = ws+OFF_SD0;
  float* sv0 = ws+OFF_SV0;
  unsigned* pm0=(unsigned*)(ws+OFF_PM0);
  float* eP0 = ws+OFF_EP0;  float* eN0 = ws+OFF_EN0;
  float* cP0 = ws+OFF_CPP0; float* cN0 = ws+OFF_CPN0;
  float* rP0 = ws+OFF_RAWP0; float* rN0 = ws+OFF_RAWN0;
  float* bP0 = ws+OFF_BP0;  float* bN0 = ws+OFF_BN0;
  float* tP0 = ws+OFF_TPP0; float* tN0 = ws+OFF_TPN0;
  float* hp1 = ws+OFF_HP1;
  float* ss1 = ws+OFF_SS1;  float* sd1 = ws+OFF_SD1;
  float* sv1 = ws+OFF_SV1;
  unsigned* pm1=(unsigned*)(ws+OFF_PM1);
  float* eP1 = ws+OFF_EP1;  float* eN1 = ws+OFF_EN1;
  float* cP1 = ws+OFF_CPP1; float* cN1 = ws+OFF_CPN1;
  float* rP1 = ws+OFF_RAWP1; float* rN1 = ws+OFF_RAWN1;
  float* bP1 = ws+OFF_BP1;  float* bN1 = ws+OFF_BN1;
  float* tP1 = ws+OFF_TPP1; float* tN1 = ws+OFF_TPN1;

  // ---- layer 0 ----
  kstats<64><<<128,256,0,stream>>>(x,s0p,acc1);
  kproj0<<<256,256,0,stream>>>(x,s0p,w0,as0,ad0,hp0,ss0,sd0);
  ksortmerge<<<16,1024,0,stream>>>(sd0,sv0,pm0,eP0,eN0);
  ktables0<<<528,256,0,stream>>>(pm0,eP0,eN0,hp0,tP0,tN0,rP0,rN0,cP0,cN0);
  kscan<32><<<32,256,0,stream>>>(rP0,rN0,bP0,bN0,tP0,tN0);
  keval0<<<8192,256,0,stream>>>(ss0,sv0,bP0,bN0,tP0,tN0,cP0,cN0,b0,elu,acc1);
  // ---- layer 1 ----
  kproj1<<<256,256,0,stream>>>(elu,acc1,w1,as1,ad1,hp1,ss1,sd1);
  ksortmerge<<<4,1024,0,stream>>>(sd1,sv1,pm1,eP1,eN1);
  ktables1<<<260,256,0,stream>>>(pm1,eP1,eN1,hp1,tP1,tN1,rP1,rN1,cP1,cN1);
  kscan<64><<<8,256,0,stream>>>(rP1,rN1,bP1,bN1,tP1,tN1);
  keval1<<<4096,256,0,stream>>>(ss1,sv1,bP1,bN1,tP1,tN1,cP1,cN1,b1,out);
}

// Round 5
// 216.829 us; speedup vs baseline: 1.3089x; 1.3089x over previous
//
#include <hip/hip_runtime.h>
#include <math.h>

#define N_ 4096

// ---------------- workspace float offsets -----------------------------------
static constexpr size_t OFF_HP0    = 2048;     // [16][4096][32]; ELU aliases
static constexpr size_t OFF_ELU    = 2048;     // [4][4096][128]
static constexpr size_t OFF_SS0    = 2099200;
static constexpr size_t OFF_SD0    = 2164736;
static constexpr size_t OFF_RUNS0  = 2230272;  // u64[16][4096]
static constexpr size_t OFF_SV0    = 2361344;
static constexpr size_t OFF_PM0    = 2426880;
static constexpr size_t OFF_EP0    = 2492416;
static constexpr size_t OFF_EN0    = 2557952;
static constexpr size_t OFF_CPP0   = 2623488;  // [16][4097] scalar count prefixes
static constexpr size_t OFF_CPN0   = 2689040;
static constexpr size_t OFF_RAWP0  = 2754592;  // [16][256][32]
static constexpr size_t OFF_RAWN0  = 2885664;
static constexpr size_t OFF_BP0    = 3016736;  // [16][257][32]
static constexpr size_t OFF_BN0    = 3148320;
static constexpr size_t OFF_TPP0   = 3279904;  // [16][4097][32]
static constexpr size_t OFF_TPN0   = 5377568;  // ends 7475232
// ---- layer1 aliases TPP0/TPN0 region (dead after keval0) ----
static constexpr size_t OFF_HP1    = 3279904;  // [4][4096][64]
static constexpr size_t OFF_SS1    = 4328480;
static constexpr size_t OFF_SD1    = 4344864;
static constexpr size_t OFF_RUNS1  = 4361248;  // u64[4][4096]
static constexpr size_t OFF_SV1    = 4394016;
static constexpr size_t OFF_PM1    = 4410400;
static constexpr size_t OFF_EP1    = 4426784;
static constexpr size_t OFF_EN1    = 4443168;
static constexpr size_t OFF_CPP1   = 4459552;  // [4][4097]
static constexpr size_t OFF_CPN1   = 4475940;
static constexpr size_t OFF_RAWP1  = 4492328;  // [4][256][64]
static constexpr size_t OFF_RAWN1  = 4557864;
static constexpr size_t OFF_BP1    = 4623400;  // [4][257][64]
static constexpr size_t OFF_BN1    = 4689192;
static constexpr size_t OFF_TPP1   = 4754984;  // [4][4097][64]
static constexpr size_t OFF_TPN1   = 5803816;  // ends 6852648
// ---- stats partials: past TPN0 end (7475232) — no aliasing -----------------
static constexpr size_t OFF_S0P    = 7475232;  // [4][32][64][2]  = 16384
static constexpr size_t OFF_S1P    = 7491616;  // [4][32][128][2] = 32768; end 7524384 ~30 MB

__device__ __forceinline__ unsigned f2s(float f){
  unsigned u=__float_as_uint(f);
  return u^((u&0x80000000u)?0xFFFFFFFFu:0x80000000u);
}
__device__ __forceinline__ float s2f(unsigned s){
  unsigned u=(s&0x80000000u)?(s^0x80000000u):~s;
  return __uint_as_float(u);
}
__device__ __forceinline__ void fma4(float4& a, float s, float4 w){
  a.x+=s*w.x; a.y+=s*w.y; a.z+=s*w.z; a.w+=s*w.w;
}
__device__ __forceinline__ float dot4(float4 a, float4 b){
  return a.x*b.x+a.y*b.y+a.z*b.z+a.w*b.w;
}

// ---------- partial stats (coalesced); per-block partials, NO atomics --------
template<int C>
__global__ void kstats(const float* __restrict__ x, float* __restrict__ statsP){
  int blk=blockIdx.x; int b=blk>>5;
  int tid=threadIdx.x;
  const int RPT=256/C;
  const int IT=128/RPT;
  int c=tid%C, rl=tid/C;
  const float* xb=x+(size_t)b*N_*C;
  float s1=0.f,s2=0.f;
  int r0=(blk&31)*128+rl;
  for(int i=0;i<IT;i++){
    float v=xb[(size_t)(r0+i*RPT)*C+c];
    s1+=v;s2+=v*v;
  }
  __shared__ float sh1[256],sh2[256];
  sh1[tid]=s1;sh2[tid]=s2;__syncthreads();
  if(tid<C){
    float a1=0.f,a2=0.f;
    for(int g=0;g<RPT;g++){a1+=sh1[g*C+tid];a2+=sh2[g*C+tid];}
    statsP[((size_t)blk*C+tid)*2+0]=a1;
    statsP[((size_t)blk*C+tid)*2+1]=a2;
  }
}

// ---------- layer0 projection: R=4 rows/lane, 8 cols/wave --------------------
__global__ void __launch_bounds__(256) kproj0(
                       const float* __restrict__ x, const float* __restrict__ statsP,
                       const float* __restrict__ w0, const float* __restrict__ asrc,
                       const float* __restrict__ adst, float* __restrict__ hp,
                       float* __restrict__ ss, float* __restrict__ sd){
  __shared__ float4 w4[512];            // [64 d][8 q] head-h slice (8 KB)
  __shared__ float mean[64],rstd[64];
  __shared__ float red1[256],red2[256];
  __shared__ float ssP[1024],sdP[1024]; // [4 wave][256 rowslot]
  int tid=threadIdx.x;
  int blk=blockIdx.x;
  int b=blk>>6, h=(blk>>4)&3, nb=blk&15;
  const float4* wg=(const float4*)w0+(size_t)h*512;
  w4[tid]=wg[tid]; w4[tid+256]=wg[tid+256];
  {
    int tc=tid&63, tg=tid>>6;
    float a1=0.f,a2=0.f;
    #pragma unroll 2
    for(int g=tg*8;g<tg*8+8;g++){
      a1+=statsP[((size_t)(b*32+g)*64+tc)*2+0];
      a2+=statsP[((size_t)(b*32+g)*64+tc)*2+1];
    }
    red1[tid]=a1; red2[tid]=a2;
  }
  __syncthreads();
  if(tid<64){
    float s1=red1[tid]+red1[tid+64]+red1[tid+128]+red1[tid+192];
    float s2=red2[tid]+red2[tid+64]+red2[tid+128]+red2[tid+192];
    float mu=s1*(1.0f/N_);
    float var=s2*(1.0f/N_)-mu*mu;
    mean[tid]=mu; rstd[tid]=rsqrtf(var+1e-5f);
  }
  __syncthreads();
  int w=tid>>6, lane=tid&63;
  int n0=nb*256+lane;
  const float4* xb=(const float4*)(x+((size_t)b*N_+n0)*64);
  float4 acc[4][2];
  #pragma unroll
  for(int r=0;r<4;r++){acc[r][0]=make_float4(0,0,0,0);acc[r][1]=make_float4(0,0,0,0);}
  for(int ch=0;ch<8;ch++){
    float4 wr[8][2];
    #pragma unroll
    for(int dd=0;dd<8;dd++){
      wr[dd][0]=w4[(ch*8+dd)*8+w*2+0];
      wr[dd][1]=w4[(ch*8+dd)*8+w*2+1];
    }
    float4 mn0=*(const float4*)&mean[ch*8], mn1=*(const float4*)&mean[ch*8+4];
    float4 rs0=*(const float4*)&rstd[ch*8], rs1=*(const float4*)&rstd[ch*8+4];
    #pragma unroll
    for(int r=0;r<4;r++){
      float4 t0=xb[(size_t)r*1024+ch*2+0];
      float4 t1=xb[(size_t)r*1024+ch*2+1];
      float hv[8];
      hv[0]=(t0.x-mn0.x)*rs0.x; hv[1]=(t0.y-mn0.y)*rs0.y;
      hv[2]=(t0.z-mn0.z)*rs0.z; hv[3]=(t0.w-mn0.w)*rs0.w;
      hv[4]=(t1.x-mn1.x)*rs1.x; hv[5]=(t1.y-mn1.y)*rs1.y;
      hv[6]=(t1.z-mn1.z)*rs1.z; hv[7]=(t1.w-mn1.w)*rs1.w;
      #pragma unroll
      for(int dd=0;dd<8;dd++){
        fma4(acc[r][0],hv[dd],wr[dd][0]);
        fma4(acc[r][1],hv[dd],wr[dd][1]);
      }
    }
  }
  float4 a1v0=((const float4*)asrc)[h*8+w*2+0];
  float4 a1v1=((const float4*)asrc)[h*8+w*2+1];
  float4 a2v0=((const float4*)adst)[h*8+w*2+0];
  float4 a2v1=((const float4*)adst)[h*8+w*2+1];
  int p=b*4+h;
  #pragma unroll
  for(int r=0;r<4;r++){
    ssP[w*256+r*64+lane]=dot4(acc[r][0],a1v0)+dot4(acc[r][1],a1v1);
    sdP[w*256+r*64+lane]=dot4(acc[r][0],a2v0)+dot4(acc[r][1],a2v1);
    float4* o4=(float4*)(hp+((size_t)p*N_+n0+r*64)*32+w*8);
    o4[0]=acc[r][0]; o4[1]=acc[r][1];
  }
  __syncthreads();
  {
    float s=ssP[tid]+ssP[256+tid]+ssP[512+tid]+ssP[768+tid];
    float d=sdP[tid]+sdP[256+tid]+sdP[512+tid]+sdP[768+tid];
    ss[(size_t)p*N_+nb*256+tid]=s;
    sd[(size_t)p*N_+nb*256+tid]=d;
  }
}

// ---------- layer1 projection: R=4 rows/lane, 4 cols/wave, 16 col-groups -----
__global__ void __launch_bounds__(256) kproj1(
                       const float* __restrict__ x, const float* __restrict__ statsP,
                       const float* __restrict__ w1, const float* __restrict__ asrc,
                       const float* __restrict__ adst, float* __restrict__ hp,
                       float* __restrict__ ss, float* __restrict__ sd){
  __shared__ float4 w4[512];            // [128 d][4 c] col-slice of cgq (8 KB)
  __shared__ float wa[128],wd[128],mean[128],rstd[128];
  __shared__ float red1[256],red2[256];
  int tid=threadIdx.x;
  int blk=blockIdx.x;
  int b=blk>>6, cgq=(blk>>4)&3, nb=blk&15;
  {
    const float4* wg=(const float4*)w1;
    int i=tid;       int d=i>>2, c=i&3; w4[i]=wg[d*16+cgq*4+c];
    i=tid+256;       d=i>>2;     c=i&3; w4[i]=wg[d*16+cgq*4+c];
  }
  {
    int tc=tid&127, tg=tid>>7;
    float a1=0.f,a2=0.f;
    #pragma unroll 4
    for(int g=tg*16;g<tg*16+16;g++){
      a1+=statsP[((size_t)(b*32+g)*128+tc)*2+0];
      a2+=statsP[((size_t)(b*32+g)*128+tc)*2+1];
    }
    red1[tid]=a1; red2[tid]=a2;
  }
  __syncthreads();
  if(tid<128){
    float s1a=0.f,s2a=0.f;
    for(int k=0;k<64;k++){float wv=w1[tid*64+k];s1a+=wv*asrc[k];s2a+=wv*adst[k];}
    wa[tid]=s1a;wd[tid]=s2a;
    float s1=red1[tid]+red1[tid+128];
    float s2=red2[tid]+red2[tid+128];
    float mu=s1*(1.0f/N_);
    float var=s2*(1.0f/N_)-mu*mu;
    mean[tid]=mu; rstd[tid]=rsqrtf(var+1e-5f);
  }
  __syncthreads();
  int w=tid>>6, lane=tid&63;
  int cg=cgq*4+w;
  int n0=nb*256+lane;
  const float4* xb=(const float4*)(x+((size_t)b*N_+n0)*128);
  float4 acc[4];
  #pragma unroll
  for(int r=0;r<4;r++) acc[r]=make_float4(0,0,0,0);
  float s1a[4]={0.f,0.f,0.f,0.f}, s2a[4]={0.f,0.f,0.f,0.f};
  bool dosum=(cgq==0)&&(w==0);
  for(int ch=0;ch<16;ch++){
    float4 wr[8];
    #pragma unroll
    for(int dd=0;dd<8;dd++) wr[dd]=w4[(ch*8+dd)*4+w];
    float4 mn0=*(const float4*)&mean[ch*8], mn1=*(const float4*)&mean[ch*8+4];
    float4 rs0=*(const float4*)&rstd[ch*8], rs1=*(const float4*)&rstd[ch*8+4];
    float4 wa0,wa1,wd0,wd1;
    if(dosum){
      wa0=*(const float4*)&wa[ch*8]; wa1=*(const float4*)&wa[ch*8+4];
      wd0=*(const float4*)&wd[ch*8]; wd1=*(const float4*)&wd[ch*8+4];
    }
    #pragma unroll
    for(int r=0;r<4;r++){
      float4 t0=xb[(size_t)r*2048+ch*2+0];
      float4 t1=xb[(size_t)r*2048+ch*2+1];
      float hv[8];
      hv[0]=(t0.x-mn0.x)*rs0.x; hv[1]=(t0.y-mn0.y)*rs0.y;
      hv[2]=(t0.z-mn0.z)*rs0.z; hv[3]=(t0.w-mn0.w)*rs0.w;
      hv[4]=(t1.x-mn1.x)*rs1.x; hv[5]=(t1.y-mn1.y)*rs1.y;
      hv[6]=(t1.z-mn1.z)*rs1.z; hv[7]=(t1.w-mn1.w)*rs1.w;
      #pragma unroll
      for(int dd=0;dd<8;dd++) fma4(acc[r],hv[dd],wr[dd]);
      if(dosum){
        s1a[r]+=hv[0]*wa0.x+hv[1]*wa0.y+hv[2]*wa0.z+hv[3]*wa0.w
               +hv[4]*wa1.x+hv[5]*wa1.y+hv[6]*wa1.z+hv[7]*wa1.w;
        s2a[r]+=hv[0]*wd0.x+hv[1]*wd0.y+hv[2]*wd0.z+hv[3]*wd0.w
               +hv[4]*wd1.x+hv[5]*wd1.y+hv[6]*wd1.z+hv[7]*wd1.w;
      }
    }
  }
  #pragma unroll
  for(int r=0;r<4;r++){
    float4* o4=(float4*)(hp+((size_t)b*N_+n0+r*64)*64+cg*4);
    o4[0]=acc[r];
  }
  if(dosum){
    #pragma unroll
    for(int r=0;r<4;r++){
      ss[(size_t)b*N_+n0+r*64]=s1a[r];
      sd[(size_t)b*N_+n0+r*64]=s2a[r];
    }
  }
}

// ---------- sort runs of 1024 (packed u64 = key<<32 | orig_idx) --------------
__global__ void __launch_bounds__(256) ksort_runs(const float* __restrict__ sdst,
                                                  unsigned long long* __restrict__ runs){
  __shared__ unsigned long long sm[1024];
  int p=blockIdx.x>>2, run=blockIdx.x&3;
  int tid=threadIdx.x;
  const float* s=sdst+(size_t)p*N_+run*1024;
  for(int l=tid;l<1024;l+=256){
    unsigned key=f2s(s[l]);
    sm[l]=((unsigned long long)key<<32)|(unsigned)(run*1024+l);
  }
  for(unsigned k=2;k<=1024u;k<<=1)
    for(unsigned j=k>>1;j>0;j>>=1){
      __syncthreads();
      for(unsigned t=tid;t<512u;t+=256u){
        unsigned i=((t&~(j-1))<<1)|(t&(j-1));
        unsigned q=i|j;
        bool up=((i&k)==0);
        unsigned long long a=sm[i],b=sm[q];
        if((a>b)==up){sm[i]=b;sm[q]=a;}
      }
    }
  __syncthreads();
  unsigned long long* rg=runs+(size_t)p*N_+run*1024;
  for(int l=tid;l<1024;l+=256) rg[l]=sm[l];
}

// ---------- merge 4 sorted runs by rank (binary search in LDS) ---------------
__global__ void __launch_bounds__(1024) kmerge(const unsigned long long* __restrict__ runs,
    float* __restrict__ sv, unsigned* __restrict__ perm,
    float* __restrict__ eP, float* __restrict__ eN){
  __shared__ unsigned long long sm[4096];
  int p=blockIdx.x>>2, cg=blockIdx.x&3;
  int tid=threadIdx.x;
  const unsigned long long* rg=runs+(size_t)p*N_;
  for(int l=tid;l<4096;l+=1024) sm[l]=rg[l];
  __syncthreads();
  unsigned long long e=sm[cg*1024+tid];
  int rank=tid;
  #pragma unroll
  for(int o=0;o<4;o++){
    if(o==cg) continue;
    const unsigned long long* base=sm+o*1024;
    int lo=0,hi=1024;
    while(lo<hi){int mid=(lo+hi)>>1; if(base[mid]<e) lo=mid+1; else hi=mid;}
    rank+=lo;
  }
  unsigned long long mk=sm[1023];
  if(sm[2047]>mk) mk=sm[2047];
  if(sm[3071]>mk) mk=sm[3071];
  if(sm[4095]>mk) mk=sm[4095];
  float m=s2f((unsigned)(mk>>32));
  float v=s2f((unsigned)(e>>32));
  size_t o=(size_t)p*N_+rank;
  sv[o]=v;
  perm[o]=(unsigned)(e&0xffffffffu);
  eP[o]=expf(v-m);
  eN[o]=expf(0.2f*(v-m));
}

// ---------- counts role-block: absolute scalar count prefixes for one p ------
__device__ __forceinline__ void counts_block(const float* __restrict__ eP,
    const float* __restrict__ eN, float* __restrict__ CPP, float* __restrict__ CPN,
    int p, float* s){
  int t=threadIdx.x;
  for(int pass=0;pass<2;pass++){
    const float* e=pass?eN:eP;
    float* C=pass?CPN:CPP;
    const float4* e4=(const float4*)(e+(size_t)p*N_);
    float4 a0=e4[t*4+0],a1=e4[t*4+1],a2=e4[t*4+2],a3=e4[t*4+3];
    float lp=a0.x+a0.y+a0.z+a0.w+a1.x+a1.y+a1.z+a1.w
            +a2.x+a2.y+a2.z+a2.w+a3.x+a3.y+a3.z+a3.w;
    if(pass) __syncthreads();
    s[t]=lp; __syncthreads();
    for(int off=1;off<256;off<<=1){
      float tv=(t>=off)?s[t-off]:0.f;
      __syncthreads();
      s[t]+=tv;
      __syncthreads();
    }
    float bp=s[t]-lp;
    size_t o=(size_t)p*4097+(size_t)t*16;
    C[o+ 0]=bp; bp+=a0.x; C[o+ 1]=bp; bp+=a0.y; C[o+ 2]=bp; bp+=a0.z; C[o+ 3]=bp; bp+=a0.w;
    C[o+ 4]=bp; bp+=a1.x; C[o+ 5]=bp; bp+=a1.y; C[o+ 6]=bp; bp+=a1.z; C[o+ 7]=bp; bp+=a1.w;
    C[o+ 8]=bp; bp+=a2.x; C[o+ 9]=bp; bp+=a2.y; C[o+10]=bp; bp+=a2.z; C[o+11]=bp; bp+=a2.w;
    C[o+12]=bp; bp+=a3.x; C[o+13]=bp; bp+=a3.y; C[o+14]=bp; bp+=a3.z; C[o+15]=bp;
    if(t==255) C[(size_t)p*4097+4096]=s[255];
  }
}

// ---------- layer0 relative tables + fused counts (blocks 0..15) -------------
__global__ void __launch_bounds__(256) ktables0(const unsigned* __restrict__ perm,
    const float* __restrict__ eP, const float* __restrict__ eN,
    const float* __restrict__ hp, float* __restrict__ TPP, float* __restrict__ TPN,
    float* __restrict__ rawP, float* __restrict__ rawN,
    float* __restrict__ CPP, float* __restrict__ CPN){
  __shared__ float s[256];
  if(blockIdx.x<16){ counts_block(eP,eN,CPP,CPN,blockIdx.x,s); return; }
  int gw=((blockIdx.x-16)*256+threadIdx.x)>>6;   // 0..2047
  int lane=threadIdx.x&63, half=lane>>5, ch=lane&31;
  int cglob=gw*2+half;
  int p=cglob>>8, c=cglob&255;
  float aP=0.f,aN=0.f;
  for(int q=0;q<16;q++){
    int r=c*16+q;
    size_t ro=(size_t)p*N_+r;
    float ep=eP[ro],en=eN[ro];
    unsigned pr=perm[ro];
    float hv=hp[((size_t)p*N_+pr)*32+ch];
    size_t to=((size_t)p*4097+r)*32+ch;
    TPP[to]=aP; TPN[to]=aN;
    aP+=ep*hv; aN+=en*hv;
  }
  size_t bo=((size_t)p*256+c)*32+ch;
  rawP[bo]=aP; rawN[bo]=aN;
}

// ---------- layer1 relative tables + fused counts (blocks 0..3) --------------
__global__ void __launch_bounds__(256) ktables1(const unsigned* __restrict__ perm,
    const float* __restrict__ eP, const float* __restrict__ eN,
    const float* __restrict__ hp, float* __restrict__ TPP, float* __restrict__ TPN,
    float* __restrict__ rawP, float* __restrict__ rawN,
    float* __restrict__ CPP, float* __restrict__ CPN){
  __shared__ float s[256];
  if(blockIdx.x<4){ counts_block(eP,eN,CPP,CPN,blockIdx.x,s); return; }
  int wid=((blockIdx.x-4)*256+threadIdx.x)>>6;   // 0..1023
  int lane=threadIdx.x&63;
  int p=wid>>8, c=wid&255;
  float aP=0.f,aN=0.f;
  for(int q=0;q<16;q++){
    int r=c*16+q;
    size_t ro=(size_t)p*N_+r;
    float ep=eP[ro],en=eN[ro];
    unsigned pr=perm[ro];
    float hv=hp[((size_t)p*N_+pr)*64+lane];
    size_t to=((size_t)p*4097+r)*64+lane;
    TPP[to]=aP; TPN[to]=aN;
    aP+=ep*hv; aN+=en*hv;
  }
  size_t bo=((size_t)p*256+c)*64+lane;
  rawP[bo]=aP; rawN[bo]=aN;
}

// ---------- scan chunk sums -> bases; totals -> table row 4096 ---------------
template<int D>
__global__ void __launch_bounds__(256) kscan(const float* __restrict__ rawP,
    const float* __restrict__ rawN, float* __restrict__ bP, float* __restrict__ bN,
    float* __restrict__ TPP, float* __restrict__ TPN){
  __shared__ float ssum[256];
  int p=blockIdx.x>>1, pass=blockIdx.x&1;
  const float* src=pass?rawN:rawP;
  float* dst=pass?bN:bP;
  float* tp=pass?TPN:TPP;
  int tid=threadIdx.x;
  constexpr int SEG=256/D;
  int ch=tid&(D-1), sg=tid/D;
  const float* s0=src+(size_t)p*256*D;
  float acc=0.f;
  for(int c=sg*D;c<sg*D+D;c++) acc+=s0[c*D+ch];
  ssum[tid]=acc; __syncthreads();
  float base=0.f, tot=0.f;
  #pragma unroll
  for(int g=0;g<SEG;g++){float v=ssum[g*D+ch]; tot+=v; if(g<sg) base+=v;}
  float r=base;
  for(int c=sg*D;c<sg*D+D;c++){
    dst[((size_t)p*257+c)*D+ch]=r;
    r+=s0[c*D+ch];
  }
  if(sg==0){
    dst[((size_t)p*257+256)*D+ch]=0.f;
    tp[((size_t)p*4097+4096)*D+ch]=tot;
  }
}

// ---------- layer0 row eval: LDS-staged search levels (p uniform per block) --
__global__ void __launch_bounds__(256) keval0(const float* __restrict__ ss,
                       const float* __restrict__ sv,
                       const float* __restrict__ bP, const float* __restrict__ bN,
                       const float* __restrict__ TPP, const float* __restrict__ TPN,
                       const float* __restrict__ CPP, const float* __restrict__ CPN,
                       const float* __restrict__ bias, float* __restrict__ out){
  __shared__ float l1[32];      // level1 samples: svp[c*128+127]
  __shared__ float l2[1024];    // level2 samples: svp[c1*128+q*4+3]
  int tid=threadIdx.x;
  int blk=blockIdx.x;
  int p=blk>>9;                 // 512 blocks per p; uniform per block
  const float* svp=sv+(size_t)p*N_;
  for(int i=tid;i<1024;i+=256) l2[i]=svp[(i>>5)*128+(i&31)*4+3];
  if(tid<32) l1[tid]=svp[tid*128+127];
  __syncthreads();
  int gw=(blk*256+tid)>>6;
  int lane=tid&63, half=lane>>5, ch=lane&31;
  int row=gw*2+half;
  int i=row&4095;
  int b=p>>2, h=p&3;
  float ssrc=ss[(size_t)p*N_+i];
  float m=l2[1023];             // == svp[4095]
  float xx=ssrc+m;
  float M=xx>0.f?xx:0.2f*xx;
  float fpos=expf(xx-M),fneg=expf(0.2f*xx-M);
  float th=-ssrc;
  float s1v=l1[ch];
  unsigned long long bal=__ballot(s1v<=th);
  int c1=half?(int)__popcll(bal>>32):(int)__popcll(bal&0xFFFFFFFFull);
  int lo;
  if(c1>=32){ lo=4096; }
  else{
    float s2v=l2[c1*32+ch];
    unsigned long long bal2=__ballot(s2v<=th);
    int c2=half?(int)__popcll(bal2>>32):(int)__popcll(bal2&0xFFFFFFFFull);
    int base=c1*128+c2*4;
    float4 qv=*((const float4*)(svp+base));
    int c3=(qv.x<=th)+(qv.y<=th)+(qv.z<=th)+(qv.w<=th);
    lo=base+c3;
  }
  int c=lo>>4;
  float relP=TPP[((size_t)p*4097+lo)*32+ch];
  float relN=TPN[((size_t)p*4097+lo)*32+ch];
  float baP=bP[((size_t)p*257+c)*32+ch];
  float baN=bN[((size_t)p*257+c)*32+ch];
  float tot=TPP[((size_t)p*4097+4096)*32+ch];
  float CPl=CPP[(size_t)p*4097+lo];
  float CNl=CPN[(size_t)p*4097+lo];
  float CT =CPP[(size_t)p*4097+4096];
  float denom=fpos*(CT-CPl)+fneg*CNl;
  float v=fpos*(tot-(baP+relP))+fneg*(baN+relN);
  float r=v/denom+bias[ch];
  r=r>0.f?r:expm1f(r);
  out[((size_t)(b*N_+i))*128+h*32+ch]=r;
}

// ---------- layer1 row eval: wave per row, LDS-staged level1 -----------------
__global__ void __launch_bounds__(256) keval1(const float* __restrict__ ss,
                       const float* __restrict__ sv,
                       const float* __restrict__ bP, const float* __restrict__ bN,
                       const float* __restrict__ TPP, const float* __restrict__ TPN,
                       const float* __restrict__ CPP, const float* __restrict__ CPN,
                       const float* __restrict__ bias, float* __restrict__ out){
  __shared__ float l1[64];      // svp[c*64+63]
  int tid=threadIdx.x;
  int blk=blockIdx.x;
  int p=blk>>10;                // 1024 blocks per p; uniform per block
  const float* svp=sv+(size_t)p*N_;
  if(tid<64) l1[tid]=svp[tid*64+63];
  __syncthreads();
  int wid=(blk*256+tid)>>6;
  int lane=tid&63;
  int i=wid&4095;
  float ssrc=ss[(size_t)p*N_+i];
  float m=l1[63];               // == svp[4095]
  float xx=ssrc+m;
  float M=xx>0.f?xx:0.2f*xx;
  float fpos=expf(xx-M),fneg=expf(0.2f*xx-M);
  float th=-ssrc;
  float s1v=l1[lane];
  int c1=(int)__popcll(__ballot(s1v<=th));
  int lo;
  if(c1>=64){ lo=4096; }
  else{
    float s2v=svp[c1*64+lane];
    lo=c1*64+(int)__popcll(__ballot(s2v<=th));
  }
  int c=lo>>4;
  float relP=TPP[((size_t)p*4097+lo)*64+lane];
  float relN=TPN[((size_t)p*4097+lo)*64+lane];
  float baP=bP[((size_t)p*257+c)*64+lane];
  float baN=bN[((size_t)p*257+c)*64+lane];
  float tot=TPP[((size_t)p*4097+4096)*64+lane];
  float CPl=CPP[(size_t)p*4097+lo];
  float CNl=CPN[(size_t)p*4097+lo];
  float CT =CPP[(size_t)p*4097+4096];
  float denom=fpos*(CT-CPl)+fneg*CNl;
  float v=fpos*(tot-(baP+relP))+fneg*(baN+relN);
  out[((size_t)p*N_+i)*64+lane]=v/denom+bias[lane];
}

extern "C" void kernel_launch(void* const* d_in, const int* in_sizes, int n_in,
                              void* d_out, int out_size, void* d_ws, size_t ws_size,
                              hipStream_t stream) {
  const float* x  =(const float*)d_in[0];
  const float* w0 =(const float*)d_in[1];
  const float* as0=(const float*)d_in[2];
  const float* ad0=(const float*)d_in[3];
  const float* b0 =(const float*)d_in[4];
  const float* w1 =(const float*)d_in[5];
  const float* as1=(const float*)d_in[6];
  const float* ad1=(const float*)d_in[7];
  const float* b1 =(const float*)d_in[8];
  float* ws=(float*)d_ws;
  float* out=(float*)d_out;

  float* s0p = ws+OFF_S0P;
  float* s1p = ws+OFF_S1P;
  float* hp0 = ws+OFF_HP0;
  float* elu = ws+OFF_ELU;
  float* ss0 = ws+OFF_SS0;  float* sd0 = ws+OFF_SD0;
  unsigned long long* runs0=(unsigned long long*)(ws+OFF_RUNS0);
  float* sv0 = ws+OFF_SV0;
  unsigned* pm0=(unsigned*)(ws+OFF_PM0);
  float* eP0 = ws+OFF_EP0;  float* eN0 = ws+OFF_EN0;
  float* cP0 = ws+OFF_CPP0; float* cN0 = ws+OFF_CPN0;
  float* rP0 = ws+OFF_RAWP0; float* rN0 = ws+OFF_RAWN0;
  float* bP0 = ws+OFF_BP0;  float* bN0 = ws+OFF_BN0;
  float* tP0 = ws+OFF_TPP0; float* tN0 = ws+OFF_TPN0;
  float* hp1 = ws+OFF_HP1;
  float* ss1 = ws+OFF_SS1;  float* sd1 = ws+OFF_SD1;
  unsigned long long* runs1=(unsigned long long*)(ws+OFF_RUNS1);
  float* sv1 = ws+OFF_SV1;
  unsigned* pm1=(unsigned*)(ws+OFF_PM1);
  float* eP1 = ws+OFF_EP1;  float* eN1 = ws+OFF_EN1;
  float* cP1 = ws+OFF_CPP1; float* cN1 = ws+OFF_CPN1;
  float* rP1 = ws+OFF_RAWP1; float* rN1 = ws+OFF_RAWN1;
  float* bP1 = ws+OFF_BP1;  float* bN1 = ws+OFF_BN1;
  float* tP1 = ws+OFF_TPP1; float* tN1 = ws+OFF_TPN1;

  // ---- layer 0 ----
  kstats<64><<<128,256,0,stream>>>(x,s0p);
  kproj0<<<256,256,0,stream>>>(x,s0p,w0,as0,ad0,hp0,ss0,sd0);
  ksort_runs<<<64,256,0,stream>>>(sd0,runs0);
  kmerge<<<64,1024,0,stream>>>(runs0,sv0,pm0,eP0,eN0);
  ktables0<<<528,256,0,stream>>>(pm0,eP0,eN0,hp0,tP0,tN0,rP0,rN0,cP0,cN0);
  kscan<32><<<32,256,0,stream>>>(rP0,rN0,bP0,bN0,tP0,tN0);
  keval0<<<8192,256,0,stream>>>(ss0,sv0,bP0,bN0,tP0,tN0,cP0,cN0,b0,elu);
  // ---- layer 1 ----
  kstats<128><<<128,256,0,stream>>>(elu,s1p);
  kproj1<<<256,256,0,stream>>>(elu,s1p,w1,as1,ad1,hp1,ss1,sd1);
  ksort_runs<<<16,256,0,stream>>>(sd1,runs1);
  kmerge<<<16,1024,0,stream>>>(runs1,sv1,pm1,eP1,eN1);
  ktables1<<<260,256,0,stream>>>(pm1,eP1,eN1,hp1,tP1,tN1,rP1,rN1,cP1,cN1);
  kscan<64><<<8,256,0,stream>>>(rP1,rN1,bP1,bN1,tP1,tN1);
  keval1<<<4096,256,0,stream>>>(ss1,sv1,bP1,bN1,tP1,tN1,cP1,cN1,b1,out);
}

// Round 6
// 193.013 us; speedup vs baseline: 1.4704x; 1.1234x over previous
//
#include <hip/hip_runtime.h>
#include <math.h>

#define N_ 4096

// ---------------- workspace float offsets -----------------------------------
static constexpr size_t OFF_HP0    = 2048;     // [16][4096][32]; ELU aliases
static constexpr size_t OFF_ELU    = 2048;     // [4][4096][128]
static constexpr size_t OFF_SS0    = 2099200;
static constexpr size_t OFF_SD0    = 2164736;
static constexpr size_t OFF_RUNS0  = 2230272;  // u64[16][4096]
static constexpr size_t OFF_SV0    = 2361344;
static constexpr size_t OFF_PM0    = 2426880;
static constexpr size_t OFF_EP0    = 2492416;
static constexpr size_t OFF_EN0    = 2557952;
static constexpr size_t OFF_CPP0   = 2623488;  // [16][4097] scalar count prefixes
static constexpr size_t OFF_CPN0   = 2689040;
static constexpr size_t OFF_TPP0   = 3279904;  // [16][4097][32]
static constexpr size_t OFF_TPN0   = 5377568;  // ends 7475232
// ---- layer1 aliases TPP0/TPN0 region (dead after keval0) ----
static constexpr size_t OFF_HP1    = 3279904;  // [4][4096][64]
static constexpr size_t OFF_SS1    = 4328480;
static constexpr size_t OFF_SD1    = 4344864;
static constexpr size_t OFF_RUNS1  = 4361248;  // u64[4][4096]
static constexpr size_t OFF_SV1    = 4394016;
static constexpr size_t OFF_PM1    = 4410400;
static constexpr size_t OFF_EP1    = 4426784;
static constexpr size_t OFF_EN1    = 4443168;
static constexpr size_t OFF_CPP1   = 4459552;  // [4][4097]
static constexpr size_t OFF_CPN1   = 4475940;
static constexpr size_t OFF_TPP1   = 4754984;  // [4][4097][64]
static constexpr size_t OFF_TPN1   = 5803816;  // ends 6852648
// ---- stats partials: past TPN0 end (7475232) — no aliasing -----------------
static constexpr size_t OFF_S0P    = 7475232;  // [4][32][64][2]  = 16384
static constexpr size_t OFF_S1P    = 7491616;  // [4][32][128][2] = 32768; end 7524384
// ---- 8-row-chunk raw/base arrays (fresh, past everything) ------------------
static constexpr size_t OFF_RAWP0  = 7524384;  // [16][512][32] = 262144
static constexpr size_t OFF_RAWN0  = 7786528;
static constexpr size_t OFF_BP0    = 8048672;  // [16][513][32] = 262656
static constexpr size_t OFF_BN0    = 8311328;
static constexpr size_t OFF_RAWP1  = 8573984;  // [4][512][64]  = 131072
static constexpr size_t OFF_RAWN1  = 8705056;
static constexpr size_t OFF_BP1    = 8836128;  // [4][513][64]  = 131328
static constexpr size_t OFF_BN1    = 8967456;  // end 9098784 ~36.4 MB

__device__ __forceinline__ unsigned f2s(float f){
  unsigned u=__float_as_uint(f);
  return u^((u&0x80000000u)?0xFFFFFFFFu:0x80000000u);
}
__device__ __forceinline__ float s2f(unsigned s){
  unsigned u=(s&0x80000000u)?(s^0x80000000u):~s;
  return __uint_as_float(u);
}
__device__ __forceinline__ void fma4(float4& a, float s, float4 w){
  a.x+=s*w.x; a.y+=s*w.y; a.z+=s*w.z; a.w+=s*w.w;
}
__device__ __forceinline__ float dot4(float4 a, float4 b){
  return a.x*b.x+a.y*b.y+a.z*b.z+a.w*b.w;
}

// ---------- partial stats (coalesced); per-block partials, NO atomics --------
template<int C>
__global__ void kstats(const float* __restrict__ x, float* __restrict__ statsP){
  int blk=blockIdx.x; int b=blk>>5;
  int tid=threadIdx.x;
  const int RPT=256/C;
  const int IT=128/RPT;
  int c=tid%C, rl=tid/C;
  const float* xb=x+(size_t)b*N_*C;
  float s1=0.f,s2=0.f;
  int r0=(blk&31)*128+rl;
  for(int i=0;i<IT;i++){
    float v=xb[(size_t)(r0+i*RPT)*C+c];
    s1+=v;s2+=v*v;
  }
  __shared__ float sh1[256],sh2[256];
  sh1[tid]=s1;sh2[tid]=s2;__syncthreads();
  if(tid<C){
    float a1=0.f,a2=0.f;
    for(int g=0;g<RPT;g++){a1+=sh1[g*C+tid];a2+=sh2[g*C+tid];}
    statsP[((size_t)blk*C+tid)*2+0]=a1;
    statsP[((size_t)blk*C+tid)*2+1]=a2;
  }
}

// ---------- layer0 projection: R=4 rows/lane, 8 cols/wave --------------------
__global__ void __launch_bounds__(256) kproj0(
                       const float* __restrict__ x, const float* __restrict__ statsP,
                       const float* __restrict__ w0, const float* __restrict__ asrc,
                       const float* __restrict__ adst, float* __restrict__ hp,
                       float* __restrict__ ss, float* __restrict__ sd){
  __shared__ float4 w4[512];            // [64 d][8 q] head-h slice (8 KB)
  __shared__ float mean[64],rstd[64];
  __shared__ float red1[256],red2[256];
  __shared__ float ssP[1024],sdP[1024]; // [4 wave][256 rowslot]
  int tid=threadIdx.x;
  int blk=blockIdx.x;
  int b=blk>>6, h=(blk>>4)&3, nb=blk&15;
  const float4* wg=(const float4*)w0+(size_t)h*512;
  w4[tid]=wg[tid]; w4[tid+256]=wg[tid+256];
  {
    int tc=tid&63, tg=tid>>6;
    float a1=0.f,a2=0.f;
    #pragma unroll 2
    for(int g=tg*8;g<tg*8+8;g++){
      a1+=statsP[((size_t)(b*32+g)*64+tc)*2+0];
      a2+=statsP[((size_t)(b*32+g)*64+tc)*2+1];
    }
    red1[tid]=a1; red2[tid]=a2;
  }
  __syncthreads();
  if(tid<64){
    float s1=red1[tid]+red1[tid+64]+red1[tid+128]+red1[tid+192];
    float s2=red2[tid]+red2[tid+64]+red2[tid+128]+red2[tid+192];
    float mu=s1*(1.0f/N_);
    float var=s2*(1.0f/N_)-mu*mu;
    mean[tid]=mu; rstd[tid]=rsqrtf(var+1e-5f);
  }
  __syncthreads();
  int w=tid>>6, lane=tid&63;
  int n0=nb*256+lane;
  const float4* xb=(const float4*)(x+((size_t)b*N_+n0)*64);
  float4 acc[4][2];
  #pragma unroll
  for(int r=0;r<4;r++){acc[r][0]=make_float4(0,0,0,0);acc[r][1]=make_float4(0,0,0,0);}
  for(int ch=0;ch<8;ch++){
    float4 wr[8][2];
    #pragma unroll
    for(int dd=0;dd<8;dd++){
      wr[dd][0]=w4[(ch*8+dd)*8+w*2+0];
      wr[dd][1]=w4[(ch*8+dd)*8+w*2+1];
    }
    float4 mn0=*(const float4*)&mean[ch*8], mn1=*(const float4*)&mean[ch*8+4];
    float4 rs0=*(const float4*)&rstd[ch*8], rs1=*(const float4*)&rstd[ch*8+4];
    #pragma unroll
    for(int r=0;r<4;r++){
      float4 t0=xb[(size_t)r*1024+ch*2+0];
      float4 t1=xb[(size_t)r*1024+ch*2+1];
      float hv[8];
      hv[0]=(t0.x-mn0.x)*rs0.x; hv[1]=(t0.y-mn0.y)*rs0.y;
      hv[2]=(t0.z-mn0.z)*rs0.z; hv[3]=(t0.w-mn0.w)*rs0.w;
      hv[4]=(t1.x-mn1.x)*rs1.x; hv[5]=(t1.y-mn1.y)*rs1.y;
      hv[6]=(t1.z-mn1.z)*rs1.z; hv[7]=(t1.w-mn1.w)*rs1.w;
      #pragma unroll
      for(int dd=0;dd<8;dd++){
        fma4(acc[r][0],hv[dd],wr[dd][0]);
        fma4(acc[r][1],hv[dd],wr[dd][1]);
      }
    }
  }
  float4 a1v0=((const float4*)asrc)[h*8+w*2+0];
  float4 a1v1=((const float4*)asrc)[h*8+w*2+1];
  float4 a2v0=((const float4*)adst)[h*8+w*2+0];
  float4 a2v1=((const float4*)adst)[h*8+w*2+1];
  int p=b*4+h;
  #pragma unroll
  for(int r=0;r<4;r++){
    ssP[w*256+r*64+lane]=dot4(acc[r][0],a1v0)+dot4(acc[r][1],a1v1);
    sdP[w*256+r*64+lane]=dot4(acc[r][0],a2v0)+dot4(acc[r][1],a2v1);
    float4* o4=(float4*)(hp+((size_t)p*N_+n0+r*64)*32+w*8);
    o4[0]=acc[r][0]; o4[1]=acc[r][1];
  }
  __syncthreads();
  {
    float s=ssP[tid]+ssP[256+tid]+ssP[512+tid]+ssP[768+tid];
    float d=sdP[tid]+sdP[256+tid]+sdP[512+tid]+sdP[768+tid];
    ss[(size_t)p*N_+nb*256+tid]=s;
    sd[(size_t)p*N_+nb*256+tid]=d;
  }
}

// ---------- layer1 projection: R=4 rows/lane, 4 cols/wave, 16 col-groups -----
__global__ void __launch_bounds__(256) kproj1(
                       const float* __restrict__ x, const float* __restrict__ statsP,
                       const float* __restrict__ w1, const float* __restrict__ asrc,
                       const float* __restrict__ adst, float* __restrict__ hp,
                       float* __restrict__ ss, float* __restrict__ sd){
  __shared__ float4 w4[512];            // [128 d][4 c] col-slice of cgq (8 KB)
  __shared__ float wa[128],wd[128],mean[128],rstd[128];
  __shared__ float red1[256],red2[256];
  int tid=threadIdx.x;
  int blk=blockIdx.x;
  int b=blk>>6, cgq=(blk>>4)&3, nb=blk&15;
  {
    const float4* wg=(const float4*)w1;
    int i=tid;       int d=i>>2, c=i&3; w4[i]=wg[d*16+cgq*4+c];
    i=tid+256;       d=i>>2;     c=i&3; w4[i]=wg[d*16+cgq*4+c];
  }
  {
    int tc=tid&127, tg=tid>>7;
    float a1=0.f,a2=0.f;
    #pragma unroll 4
    for(int g=tg*16;g<tg*16+16;g++){
      a1+=statsP[((size_t)(b*32+g)*128+tc)*2+0];
      a2+=statsP[((size_t)(b*32+g)*128+tc)*2+1];
    }
    red1[tid]=a1; red2[tid]=a2;
  }
  __syncthreads();
  if(tid<128){
    float s1a=0.f,s2a=0.f;
    for(int k=0;k<64;k++){float wv=w1[tid*64+k];s1a+=wv*asrc[k];s2a+=wv*adst[k];}
    wa[tid]=s1a;wd[tid]=s2a;
    float s1=red1[tid]+red1[tid+128];
    float s2=red2[tid]+red2[tid+128];
    float mu=s1*(1.0f/N_);
    float var=s2*(1.0f/N_)-mu*mu;
    mean[tid]=mu; rstd[tid]=rsqrtf(var+1e-5f);
  }
  __syncthreads();
  int w=tid>>6, lane=tid&63;
  int cg=cgq*4+w;
  int n0=nb*256+lane;
  const float4* xb=(const float4*)(x+((size_t)b*N_+n0)*128);
  float4 acc[4];
  #pragma unroll
  for(int r=0;r<4;r++) acc[r]=make_float4(0,0,0,0);
  float s1a[4]={0.f,0.f,0.f,0.f}, s2a[4]={0.f,0.f,0.f,0.f};
  bool dosum=(cgq==0)&&(w==0);
  for(int ch=0;ch<16;ch++){
    float4 wr[8];
    #pragma unroll
    for(int dd=0;dd<8;dd++) wr[dd]=w4[(ch*8+dd)*4+w];
    float4 mn0=*(const float4*)&mean[ch*8], mn1=*(const float4*)&mean[ch*8+4];
    float4 rs0=*(const float4*)&rstd[ch*8], rs1=*(const float4*)&rstd[ch*8+4];
    float4 wa0,wa1,wd0,wd1;
    if(dosum){
      wa0=*(const float4*)&wa[ch*8]; wa1=*(const float4*)&wa[ch*8+4];
      wd0=*(const float4*)&wd[ch*8]; wd1=*(const float4*)&wd[ch*8+4];
    }
    #pragma unroll
    for(int r=0;r<4;r++){
      float4 t0=xb[(size_t)r*2048+ch*2+0];
      float4 t1=xb[(size_t)r*2048+ch*2+1];
      float hv[8];
      hv[0]=(t0.x-mn0.x)*rs0.x; hv[1]=(t0.y-mn0.y)*rs0.y;
      hv[2]=(t0.z-mn0.z)*rs0.z; hv[3]=(t0.w-mn0.w)*rs0.w;
      hv[4]=(t1.x-mn1.x)*rs1.x; hv[5]=(t1.y-mn1.y)*rs1.y;
      hv[6]=(t1.z-mn1.z)*rs1.z; hv[7]=(t1.w-mn1.w)*rs1.w;
      #pragma unroll
      for(int dd=0;dd<8;dd++) fma4(acc[r],hv[dd],wr[dd]);
      if(dosum){
        s1a[r]+=hv[0]*wa0.x+hv[1]*wa0.y+hv[2]*wa0.z+hv[3]*wa0.w
               +hv[4]*wa1.x+hv[5]*wa1.y+hv[6]*wa1.z+hv[7]*wa1.w;
        s2a[r]+=hv[0]*wd0.x+hv[1]*wd0.y+hv[2]*wd0.z+hv[3]*wd0.w
               +hv[4]*wd1.x+hv[5]*wd1.y+hv[6]*wd1.z+hv[7]*wd1.w;
      }
    }
  }
  #pragma unroll
  for(int r=0;r<4;r++){
    float4* o4=(float4*)(hp+((size_t)b*N_+n0+r*64)*64+cg*4);
    o4[0]=acc[r];
  }
  if(dosum){
    #pragma unroll
    for(int r=0;r<4;r++){
      ss[(size_t)b*N_+n0+r*64]=s1a[r];
      sd[(size_t)b*N_+n0+r*64]=s2a[r];
    }
  }
}

// ---------- sort runs of 1024; 512 threads = 1 CAS/thread/pass ---------------
__global__ void __launch_bounds__(512) ksort_runs(const float* __restrict__ sdst,
                                                  unsigned long long* __restrict__ runs){
  __shared__ unsigned long long sm[1024];
  int p=blockIdx.x>>2, run=blockIdx.x&3;
  int tid=threadIdx.x;
  const float* s=sdst+(size_t)p*N_+run*1024;
  for(int l=tid;l<1024;l+=512){
    unsigned key=f2s(s[l]);
    sm[l]=((unsigned long long)key<<32)|(unsigned)(run*1024+l);
  }
  for(unsigned k=2;k<=1024u;k<<=1)
    for(unsigned j=k>>1;j>0;j>>=1){
      __syncthreads();
      unsigned t=(unsigned)tid;
      unsigned i=((t&~(j-1))<<1)|(t&(j-1));
      unsigned q=i|j;
      bool up=((i&k)==0);
      unsigned long long a=sm[i],b=sm[q];
      if((a>b)==up){sm[i]=b;sm[q]=a;}
    }
  __syncthreads();
  unsigned long long* rg=runs+(size_t)p*N_+run*1024;
  for(int l=tid;l<1024;l+=512) rg[l]=sm[l];
}

// ---------- merge 4 sorted runs by rank (binary search in LDS) ---------------
__global__ void __launch_bounds__(1024) kmerge(const unsigned long long* __restrict__ runs,
    float* __restrict__ sv, unsigned* __restrict__ perm,
    float* __restrict__ eP, float* __restrict__ eN){
  __shared__ unsigned long long sm[4096];
  int p=blockIdx.x>>2, cg=blockIdx.x&3;
  int tid=threadIdx.x;
  const unsigned long long* rg=runs+(size_t)p*N_;
  for(int l=tid;l<4096;l+=1024) sm[l]=rg[l];
  __syncthreads();
  unsigned long long e=sm[cg*1024+tid];
  int rank=tid;
  #pragma unroll
  for(int o=0;o<4;o++){
    if(o==cg) continue;
    const unsigned long long* base=sm+o*1024;
    int lo=0,hi=1024;
    while(lo<hi){int mid=(lo+hi)>>1; if(base[mid]<e) lo=mid+1; else hi=mid;}
    rank+=lo;
  }
  unsigned long long mk=sm[1023];
  if(sm[2047]>mk) mk=sm[2047];
  if(sm[3071]>mk) mk=sm[3071];
  if(sm[4095]>mk) mk=sm[4095];
  float m=s2f((unsigned)(mk>>32));
  float v=s2f((unsigned)(e>>32));
  size_t o=(size_t)p*N_+rank;
  sv[o]=v;
  perm[o]=(unsigned)(e&0xffffffffu);
  eP[o]=expf(v-m);
  eN[o]=expf(0.2f*(v-m));
}

// ---------- counts role-block: absolute scalar count prefixes for one p ------
__device__ __forceinline__ void counts_block(const float* __restrict__ eP,
    const float* __restrict__ eN, float* __restrict__ CPP, float* __restrict__ CPN,
    int p, float* s){
  int t=threadIdx.x;
  for(int pass=0;pass<2;pass++){
    const float* e=pass?eN:eP;
    float* C=pass?CPN:CPP;
    const float4* e4=(const float4*)(e+(size_t)p*N_);
    float4 a0=e4[t*4+0],a1=e4[t*4+1],a2=e4[t*4+2],a3=e4[t*4+3];
    float lp=a0.x+a0.y+a0.z+a0.w+a1.x+a1.y+a1.z+a1.w
            +a2.x+a2.y+a2.z+a2.w+a3.x+a3.y+a3.z+a3.w;
    if(pass) __syncthreads();
    s[t]=lp; __syncthreads();
    for(int off=1;off<256;off<<=1){
      float tv=(t>=off)?s[t-off]:0.f;
      __syncthreads();
      s[t]+=tv;
      __syncthreads();
    }
    float bp=s[t]-lp;
    size_t o=(size_t)p*4097+(size_t)t*16;
    C[o+ 0]=bp; bp+=a0.x; C[o+ 1]=bp; bp+=a0.y; C[o+ 2]=bp; bp+=a0.z; C[o+ 3]=bp; bp+=a0.w;
    C[o+ 4]=bp; bp+=a1.x; C[o+ 5]=bp; bp+=a1.y; C[o+ 6]=bp; bp+=a1.z; C[o+ 7]=bp; bp+=a1.w;
    C[o+ 8]=bp; bp+=a2.x; C[o+ 9]=bp; bp+=a2.y; C[o+10]=bp; bp+=a2.z; C[o+11]=bp; bp+=a2.w;
    C[o+12]=bp; bp+=a3.x; C[o+13]=bp; bp+=a3.y; C[o+14]=bp; bp+=a3.z; C[o+15]=bp;
    if(t==255) C[(size_t)p*4097+4096]=s[255];
  }
}

// ---------- layer0 tables: 8-row chunks (2 per wave) + fused counts ----------
__global__ void __launch_bounds__(256) ktables0(const unsigned* __restrict__ perm,
    const float* __restrict__ eP, const float* __restrict__ eN,
    const float* __restrict__ hp, float* __restrict__ TPP, float* __restrict__ TPN,
    float* __restrict__ rawP, float* __restrict__ rawN,
    float* __restrict__ CPP, float* __restrict__ CPN){
  __shared__ float s[256];
  if(blockIdx.x<16){ counts_block(eP,eN,CPP,CPN,blockIdx.x,s); return; }
  int gw=((blockIdx.x-16)*256+threadIdx.x)>>6;   // 0..4095
  int lane=threadIdx.x&63, half=lane>>5, ch=lane&31;
  int cglob=gw*2+half;                           // 0..8191
  int p=cglob>>9, c=cglob&511;
  float aP=0.f,aN=0.f;
  #pragma unroll
  for(int q=0;q<8;q++){
    int r=c*8+q;
    size_t ro=(size_t)p*N_+r;
    float ep=eP[ro],en=eN[ro];
    unsigned pr=perm[ro];
    float hv=hp[((size_t)p*N_+pr)*32+ch];
    size_t to=((size_t)p*4097+r)*32+ch;
    TPP[to]=aP; TPN[to]=aN;
    aP+=ep*hv; aN+=en*hv;
  }
  size_t bo=((size_t)p*512+c)*32+ch;
  rawP[bo]=aP; rawN[bo]=aN;
}

// ---------- layer1 tables: 8-row chunks (wave per chunk) + fused counts ------
__global__ void __launch_bounds__(256) ktables1(const unsigned* __restrict__ perm,
    const float* __restrict__ eP, const float* __restrict__ eN,
    const float* __restrict__ hp, float* __restrict__ TPP, float* __restrict__ TPN,
    float* __restrict__ rawP, float* __restrict__ rawN,
    float* __restrict__ CPP, float* __restrict__ CPN){
  __shared__ float s[256];
  if(blockIdx.x<4){ counts_block(eP,eN,CPP,CPN,blockIdx.x,s); return; }
  int wid=((blockIdx.x-4)*256+threadIdx.x)>>6;   // 0..2047
  int lane=threadIdx.x&63;
  int p=wid>>9, c=wid&511;
  float aP=0.f,aN=0.f;
  #pragma unroll
  for(int q=0;q<8;q++){
    int r=c*8+q;
    size_t ro=(size_t)p*N_+r;
    float ep=eP[ro],en=eN[ro];
    unsigned pr=perm[ro];
    float hv=hp[((size_t)p*N_+pr)*64+lane];
    size_t to=((size_t)p*4097+r)*64+lane;
    TPP[to]=aP; TPN[to]=aN;
    aP+=ep*hv; aN+=en*hv;
  }
  size_t bo=((size_t)p*512+c)*64+lane;
  rawP[bo]=aP; rawN[bo]=aN;
}

// ---------- scan 512 chunk sums -> bases; totals -> table row 4096 -----------
template<int D>
__global__ void __launch_bounds__(256) kscan(const float* __restrict__ rawP,
    const float* __restrict__ rawN, float* __restrict__ bP, float* __restrict__ bN,
    float* __restrict__ TPP, float* __restrict__ TPN){
  __shared__ float ssum[256];
  int p=blockIdx.x>>1, pass=blockIdx.x&1;
  const float* src=pass?rawN:rawP;
  float* dst=pass?bN:bP;
  float* tp=pass?TPN:TPP;
  int tid=threadIdx.x;
  constexpr int SEG=256/D;          // 8 (D=32) or 4 (D=64) segments
  constexpr int CPS=512/SEG;        // chunks per segment
  int ch=tid&(D-1), sg=tid/D;
  const float* s0=src+(size_t)p*512*D;
  float acc=0.f;
  for(int c=sg*CPS;c<sg*CPS+CPS;c++) acc+=s0[(size_t)c*D+ch];
  ssum[tid]=acc; __syncthreads();
  float base=0.f, tot=0.f;
  #pragma unroll
  for(int g=0;g<SEG;g++){float v=ssum[g*D+ch]; tot+=v; if(g<sg) base+=v;}
  float r=base;
  for(int c=sg*CPS;c<sg*CPS+CPS;c++){
    dst[((size_t)p*513+c)*D+ch]=r;
    r+=s0[(size_t)c*D+ch];
  }
  if(sg==0){
    dst[((size_t)p*513+512)*D+ch]=0.f;      // base for lo==4096
    tp[((size_t)p*4097+4096)*D+ch]=tot;     // absolute channel totals
  }
}

// ---------- layer0 row eval: 2 rows per wave, 3-level ballot search ----------
__global__ void __launch_bounds__(256) keval0(const float* __restrict__ ss,
                       const float* __restrict__ sv,
                       const float* __restrict__ bP, const float* __restrict__ bN,
                       const float* __restrict__ TPP, const float* __restrict__ TPN,
                       const float* __restrict__ CPP, const float* __restrict__ CPN,
                       const float* __restrict__ bias, float* __restrict__ out){
  int gw=(blockIdx.x*256+threadIdx.x)>>6;   // 0..32767
  int lane=threadIdx.x&63, half=lane>>5, ch=lane&31;
  int row=gw*2+half;
  int p=row>>12, i=row&4095;
  int b=p>>2, h=p&3;
  const float* svp=sv+(size_t)p*N_;
  float ssrc=ss[(size_t)p*N_+i];
  float m=svp[4095];
  float xx=ssrc+m;
  float M=xx>0.f?xx:0.2f*xx;
  float fpos=expf(xx-M),fneg=expf(0.2f*xx-M);
  float th=-ssrc;
  float s1v=svp[ch*128+127];
  unsigned long long bal=__ballot(s1v<=th);
  int c1=half?(int)__popcll(bal>>32):(int)__popcll(bal&0xFFFFFFFFull);
  int lo;
  if(c1>=32){ lo=4096; }
  else{
    float s2v=svp[c1*128+ch*4+3];
    unsigned long long bal2=__ballot(s2v<=th);
    int c2=half?(int)__popcll(bal2>>32):(int)__popcll(bal2&0xFFFFFFFFull);
    int base=c1*128+c2*4;
    float4 qv=*((const float4*)(svp+base));
    int c3=(qv.x<=th)+(qv.y<=th)+(qv.z<=th)+(qv.w<=th);
    lo=base+c3;
  }
  int c=lo>>3;
  float relP=TPP[((size_t)p*4097+lo)*32+ch];
  float relN=TPN[((size_t)p*4097+lo)*32+ch];
  float baP=bP[((size_t)p*513+c)*32+ch];
  float baN=bN[((size_t)p*513+c)*32+ch];
  float tot=TPP[((size_t)p*4097+4096)*32+ch];
  float CPl=CPP[(size_t)p*4097+lo];
  float CNl=CPN[(size_t)p*4097+lo];
  float CT =CPP[(size_t)p*4097+4096];
  float denom=fpos*(CT-CPl)+fneg*CNl;
  float v=fpos*(tot-(baP+relP))+fneg*(baN+relN);
  float r=v/denom+bias[ch];
  r=r>0.f?r:expm1f(r);
  out[((size_t)(b*N_+i))*128+h*32+ch]=r;
}

// ---------- layer1 row eval: wave per row, width-64 --------------------------
__global__ void __launch_bounds__(256) keval1(const float* __restrict__ ss,
                       const float* __restrict__ sv,
                       const float* __restrict__ bP, const float* __restrict__ bN,
                       const float* __restrict__ TPP, const float* __restrict__ TPN,
                       const float* __restrict__ CPP, const float* __restrict__ CPN,
                       const float* __restrict__ bias, float* __restrict__ out){
  int wid=(blockIdx.x*256+threadIdx.x)>>6;   // p*4096+i
  int lane=threadIdx.x&63;
  int p=wid>>12, i=wid&4095;
  const float* svp=sv+(size_t)p*N_;
  float ssrc=ss[(size_t)p*N_+i];
  float m=svp[4095];
  float xx=ssrc+m;
  float M=xx>0.f?xx:0.2f*xx;
  float fpos=expf(xx-M),fneg=expf(0.2f*xx-M);
  float th=-ssrc;
  float s1v=svp[lane*64+63];
  int c1=(int)__popcll(__ballot(s1v<=th));
  int lo;
  if(c1>=64){ lo=4096; }
  else{
    float s2v=svp[c1*64+lane];
    lo=c1*64+(int)__popcll(__ballot(s2v<=th));
  }
  int c=lo>>3;
  float relP=TPP[((size_t)p*4097+lo)*64+lane];
  float relN=TPN[((size_t)p*4097+lo)*64+lane];
  float baP=bP[((size_t)p*513+c)*64+lane];
  float baN=bN[((size_t)p*513+c)*64+lane];
  float tot=TPP[((size_t)p*4097+4096)*64+lane];
  float CPl=CPP[(size_t)p*4097+lo];
  float CNl=CPN[(size_t)p*4097+lo];
  float CT =CPP[(size_t)p*4097+4096];
  float denom=fpos*(CT-CPl)+fneg*CNl;
  float v=fpos*(tot-(baP+relP))+fneg*(baN+relN);
  out[((size_t)p*N_+i)*64+lane]=v/denom+bias[lane];
}

extern "C" void kernel_launch(void* const* d_in, const int* in_sizes, int n_in,
                              void* d_out, int out_size, void* d_ws, size_t ws_size,
                              hipStream_t stream) {
  const float* x  =(const float*)d_in[0];
  const float* w0 =(const float*)d_in[1];
  const float* as0=(const float*)d_in[2];
  const float* ad0=(const float*)d_in[3];
  const float* b0 =(const float*)d_in[4];
  const float* w1 =(const float*)d_in[5];
  const float* as1=(const float*)d_in[6];
  const float* ad1=(const float*)d_in[7];
  const float* b1 =(const float*)d_in[8];
  float* ws=(float*)d_ws;
  float* out=(float*)d_out;

  float* s0p = ws+OFF_S0P;
  float* s1p = ws+OFF_S1P;
  float* hp0 = ws+OFF_HP0;
  float* elu = ws+OFF_ELU;
  float* ss0 = ws+OFF_SS0;  float* sd0 = ws+OFF_SD0;
  unsigned long long* runs0=(unsigned long long*)(ws+OFF_RUNS0);
  float* sv0 = ws+OFF_SV0;
  unsigned* pm0=(unsigned*)(ws+OFF_PM0);
  float* eP0 = ws+OFF_EP0;  float* eN0 = ws+OFF_EN0;
  float* cP0 = ws+OFF_CPP0; float* cN0 = ws+OFF_CPN0;
  float* rP0 = ws+OFF_RAWP0; float* rN0 = ws+OFF_RAWN0;
  float* bP0 = ws+OFF_BP0;  float* bN0 = ws+OFF_BN0;
  float* tP0 = ws+OFF_TPP0; float* tN0 = ws+OFF_TPN0;
  float* hp1 = ws+OFF_HP1;
  float* ss1 = ws+OFF_SS1;  float* sd1 = ws+OFF_SD1;
  unsigned long long* runs1=(unsigned long long*)(ws+OFF_RUNS1);
  float* sv1 = ws+OFF_SV1;
  unsigned* pm1=(unsigned*)(ws+OFF_PM1);
  float* eP1 = ws+OFF_EP1;  float* eN1 = ws+OFF_EN1;
  float* cP1 = ws+OFF_CPP1; float* cN1 = ws+OFF_CPN1;
  float* rP1 = ws+OFF_RAWP1; float* rN1 = ws+OFF_RAWN1;
  float* bP1 = ws+OFF_BP1;  float* bN1 = ws+OFF_BN1;
  float* tP1 = ws+OFF_TPP1; float* tN1 = ws+OFF_TPN1;

  // ---- layer 0 ----
  kstats<64><<<128,256,0,stream>>>(x,s0p);
  kproj0<<<256,256,0,stream>>>(x,s0p,w0,as0,ad0,hp0,ss0,sd0);
  ksort_runs<<<64,512,0,stream>>>(sd0,runs0);
  kmerge<<<64,1024,0,stream>>>(runs0,sv0,pm0,eP0,eN0);
  ktables0<<<1040,256,0,stream>>>(pm0,eP0,eN0,hp0,tP0,tN0,rP0,rN0,cP0,cN0);
  kscan<32><<<32,256,0,stream>>>(rP0,rN0,bP0,bN0,tP0,tN0);
  keval0<<<8192,256,0,stream>>>(ss0,sv0,bP0,bN0,tP0,tN0,cP0,cN0,b0,elu);
  // ---- layer 1 ----
  kstats<128><<<128,256,0,stream>>>(elu,s1p);
  kproj1<<<256,256,0,stream>>>(elu,s1p,w1,as1,ad1,hp1,ss1,sd1);
  ksort_runs<<<16,512,0,stream>>>(sd1,runs1);
  kmerge<<<16,1024,0,stream>>>(runs1,sv1,pm1,eP1,eN1);
  ktables1<<<516,256,0,stream>>>(pm1,eP1,eN1,hp1,tP1,tN1,rP1,rN1,cP1,cN1);
  kscan<64><<<8,256,0,stream>>>(rP1,rN1,bP1,bN1,tP1,tN1);
  keval1<<<4096,256,0,stream>>>(ss1,sv1,bP1,bN1,tP1,tN1,cP1,cN1,b1,out);
}

// Round 7
// 191.857 us; speedup vs baseline: 1.4792x; 1.0060x over previous
//
#include <hip/hip_runtime.h>
#include <math.h>

#define N_ 4096

// ---------------- workspace float offsets -----------------------------------
static constexpr size_t OFF_HP0    = 2048;     // [16][4096][32]; ELU aliases
static constexpr size_t OFF_ELU    = 2048;     // [4][4096][128]
static constexpr size_t OFF_SS0    = 2099200;
static constexpr size_t OFF_SD0    = 2164736;
static constexpr size_t OFF_RUNS0  = 2230272;  // u64[16][4096]
static constexpr size_t OFF_SV0    = 2361344;
static constexpr size_t OFF_PM0    = 2426880;
static constexpr size_t OFF_EP0    = 2492416;
static constexpr size_t OFF_EN0    = 2557952;
static constexpr size_t OFF_CPP0   = 2623488;  // [16][4097] scalar count prefixes
static constexpr size_t OFF_CPN0   = 2689040;
static constexpr size_t OFF_TPP0   = 3279904;  // [16][4097][32]
static constexpr size_t OFF_TPN0   = 5377568;  // ends 7475232
// ---- layer1 aliases TPP0/TPN0 region (dead after keval0) ----
static constexpr size_t OFF_HP1    = 3279904;  // [4][4096][64]
static constexpr size_t OFF_SS1    = 4328480;
static constexpr size_t OFF_SD1    = 4344864;
static constexpr size_t OFF_RUNS1  = 4361248;  // u64[4][4096]
static constexpr size_t OFF_SV1    = 4394016;
static constexpr size_t OFF_PM1    = 4410400;
static constexpr size_t OFF_EP1    = 4426784;
static constexpr size_t OFF_EN1    = 4443168;
static constexpr size_t OFF_CPP1   = 4459552;  // [4][4097]
static constexpr size_t OFF_CPN1   = 4475940;
static constexpr size_t OFF_TPP1   = 4754984;  // [4][4097][64]
static constexpr size_t OFF_TPN1   = 5803816;  // ends 6852648
// ---- stats partials: past TPN0 end (7475232) — no aliasing -----------------
static constexpr size_t OFF_S0P    = 7475232;  // [4][32][64][2]  = 16384
static constexpr size_t OFF_S1P    = 7491616;  // [4][32][128][2] = 32768; end 7524384
// ---- 8-row-chunk raw/base arrays (fresh, past everything) ------------------
static constexpr size_t OFF_RAWP0  = 7524384;  // [16][512][32] = 262144
static constexpr size_t OFF_RAWN0  = 7786528;
static constexpr size_t OFF_BP0    = 8048672;  // [16][513][32] = 262656
static constexpr size_t OFF_BN0    = 8311328;
static constexpr size_t OFF_RAWP1  = 8573984;  // [4][512][64]  = 131072
static constexpr size_t OFF_RAWN1  = 8705056;
static constexpr size_t OFF_BP1    = 8836128;  // [4][513][64]  = 131328
static constexpr size_t OFF_BN1    = 8967456;  // end 9098784 ~36.4 MB

__device__ __forceinline__ unsigned f2s(float f){
  unsigned u=__float_as_uint(f);
  return u^((u&0x80000000u)?0xFFFFFFFFu:0x80000000u);
}
__device__ __forceinline__ float s2f(unsigned s){
  unsigned u=(s&0x80000000u)?(s^0x80000000u):~s;
  return __uint_as_float(u);
}
__device__ __forceinline__ void fma4(float4& a, float s, float4 w){
  a.x+=s*w.x; a.y+=s*w.y; a.z+=s*w.z; a.w+=s*w.w;
}
__device__ __forceinline__ float dot4(float4 a, float4 b){
  return a.x*b.x+a.y*b.y+a.z*b.z+a.w*b.w;
}

// ---------- partial stats (coalesced); per-block partials, NO atomics --------
template<int C>
__global__ void kstats(const float* __restrict__ x, float* __restrict__ statsP){
  int blk=blockIdx.x; int b=blk>>5;
  int tid=threadIdx.x;
  const int RPT=256/C;
  const int IT=128/RPT;
  int c=tid%C, rl=tid/C;
  const float* xb=x+(size_t)b*N_*C;
  float s1=0.f,s2=0.f;
  int r0=(blk&31)*128+rl;
  for(int i=0;i<IT;i++){
    float v=xb[(size_t)(r0+i*RPT)*C+c];
    s1+=v;s2+=v*v;
  }
  __shared__ float sh1[256],sh2[256];
  sh1[tid]=s1;sh2[tid]=s2;__syncthreads();
  if(tid<C){
    float a1=0.f,a2=0.f;
    for(int g=0;g<RPT;g++){a1+=sh1[g*C+tid];a2+=sh2[g*C+tid];}
    statsP[((size_t)blk*C+tid)*2+0]=a1;
    statsP[((size_t)blk*C+tid)*2+1]=a2;
  }
}

// ---------- layer0 projection: R=4 rows/lane, 8 cols/wave --------------------
__global__ void __launch_bounds__(256) kproj0(
                       const float* __restrict__ x, const float* __restrict__ statsP,
                       const float* __restrict__ w0, const float* __restrict__ asrc,
                       const float* __restrict__ adst, float* __restrict__ hp,
                       float* __restrict__ ss, float* __restrict__ sd){
  __shared__ float4 w4[512];            // [64 d][8 q] head-h slice (8 KB)
  __shared__ float mean[64],rstd[64];
  __shared__ float red1[256],red2[256];
  __shared__ float ssP[1024],sdP[1024]; // [4 wave][256 rowslot]
  int tid=threadIdx.x;
  int blk=blockIdx.x;
  int b=blk>>6, h=(blk>>4)&3, nb=blk&15;
  const float4* wg=(const float4*)w0+(size_t)h*512;
  w4[tid]=wg[tid]; w4[tid+256]=wg[tid+256];
  {
    int tc=tid&63, tg=tid>>6;
    float a1=0.f,a2=0.f;
    #pragma unroll 2
    for(int g=tg*8;g<tg*8+8;g++){
      a1+=statsP[((size_t)(b*32+g)*64+tc)*2+0];
      a2+=statsP[((size_t)(b*32+g)*64+tc)*2+1];
    }
    red1[tid]=a1; red2[tid]=a2;
  }
  __syncthreads();
  if(tid<64){
    float s1=red1[tid]+red1[tid+64]+red1[tid+128]+red1[tid+192];
    float s2=red2[tid]+red2[tid+64]+red2[tid+128]+red2[tid+192];
    float mu=s1*(1.0f/N_);
    float var=s2*(1.0f/N_)-mu*mu;
    mean[tid]=mu; rstd[tid]=rsqrtf(var+1e-5f);
  }
  __syncthreads();
  int w=tid>>6, lane=tid&63;
  int n0=nb*256+lane;
  const float4* xb=(const float4*)(x+((size_t)b*N_+n0)*64);
  float4 acc[4][2];
  #pragma unroll
  for(int r=0;r<4;r++){acc[r][0]=make_float4(0,0,0,0);acc[r][1]=make_float4(0,0,0,0);}
  for(int ch=0;ch<8;ch++){
    float4 wr[8][2];
    #pragma unroll
    for(int dd=0;dd<8;dd++){
      wr[dd][0]=w4[(ch*8+dd)*8+w*2+0];
      wr[dd][1]=w4[(ch*8+dd)*8+w*2+1];
    }
    float4 mn0=*(const float4*)&mean[ch*8], mn1=*(const float4*)&mean[ch*8+4];
    float4 rs0=*(const float4*)&rstd[ch*8], rs1=*(const float4*)&rstd[ch*8+4];
    #pragma unroll
    for(int r=0;r<4;r++){
      float4 t0=xb[(size_t)r*1024+ch*2+0];
      float4 t1=xb[(size_t)r*1024+ch*2+1];
      float hv[8];
      hv[0]=(t0.x-mn0.x)*rs0.x; hv[1]=(t0.y-mn0.y)*rs0.y;
      hv[2]=(t0.z-mn0.z)*rs0.z; hv[3]=(t0.w-mn0.w)*rs0.w;
      hv[4]=(t1.x-mn1.x)*rs1.x; hv[5]=(t1.y-mn1.y)*rs1.y;
      hv[6]=(t1.z-mn1.z)*rs1.z; hv[7]=(t1.w-mn1.w)*rs1.w;
      #pragma unroll
      for(int dd=0;dd<8;dd++){
        fma4(acc[r][0],hv[dd],wr[dd][0]);
        fma4(acc[r][1],hv[dd],wr[dd][1]);
      }
    }
  }
  float4 a1v0=((const float4*)asrc)[h*8+w*2+0];
  float4 a1v1=((const float4*)asrc)[h*8+w*2+1];
  float4 a2v0=((const float4*)adst)[h*8+w*2+0];
  float4 a2v1=((const float4*)adst)[h*8+w*2+1];
  int p=b*4+h;
  #pragma unroll
  for(int r=0;r<4;r++){
    ssP[w*256+r*64+lane]=dot4(acc[r][0],a1v0)+dot4(acc[r][1],a1v1);
    sdP[w*256+r*64+lane]=dot4(acc[r][0],a2v0)+dot4(acc[r][1],a2v1);
    float4* o4=(float4*)(hp+((size_t)p*N_+n0+r*64)*32+w*8);
    o4[0]=acc[r][0]; o4[1]=acc[r][1];
  }
  __syncthreads();
  {
    float s=ssP[tid]+ssP[256+tid]+ssP[512+tid]+ssP[768+tid];
    float d=sdP[tid]+sdP[256+tid]+sdP[512+tid]+sdP[768+tid];
    ss[(size_t)p*N_+nb*256+tid]=s;
    sd[(size_t)p*N_+nb*256+tid]=d;
  }
}

// ---------- layer1 projection: R=4 rows/lane, 4 cols/wave, 16 col-groups -----
__global__ void __launch_bounds__(256) kproj1(
                       const float* __restrict__ x, const float* __restrict__ statsP,
                       const float* __restrict__ w1, const float* __restrict__ asrc,
                       const float* __restrict__ adst, float* __restrict__ hp,
                       float* __restrict__ ss, float* __restrict__ sd){
  __shared__ float4 w4[512];            // [128 d][4 c] col-slice of cgq (8 KB)
  __shared__ float wa[128],wd[128],mean[128],rstd[128];
  __shared__ float red1[256],red2[256];
  int tid=threadIdx.x;
  int blk=blockIdx.x;
  int b=blk>>6, cgq=(blk>>4)&3, nb=blk&15;
  {
    const float4* wg=(const float4*)w1;
    int i=tid;       int d=i>>2, c=i&3; w4[i]=wg[d*16+cgq*4+c];
    i=tid+256;       d=i>>2;     c=i&3; w4[i]=wg[d*16+cgq*4+c];
  }
  {
    int tc=tid&127, tg=tid>>7;
    float a1=0.f,a2=0.f;
    #pragma unroll 4
    for(int g=tg*16;g<tg*16+16;g++){
      a1+=statsP[((size_t)(b*32+g)*128+tc)*2+0];
      a2+=statsP[((size_t)(b*32+g)*128+tc)*2+1];
    }
    red1[tid]=a1; red2[tid]=a2;
  }
  __syncthreads();
  if(tid<128){
    float s1a=0.f,s2a=0.f;
    for(int k=0;k<64;k++){float wv=w1[tid*64+k];s1a+=wv*asrc[k];s2a+=wv*adst[k];}
    wa[tid]=s1a;wd[tid]=s2a;
    float s1=red1[tid]+red1[tid+128];
    float s2=red2[tid]+red2[tid+128];
    float mu=s1*(1.0f/N_);
    float var=s2*(1.0f/N_)-mu*mu;
    mean[tid]=mu; rstd[tid]=rsqrtf(var+1e-5f);
  }
  __syncthreads();
  int w=tid>>6, lane=tid&63;
  int cg=cgq*4+w;
  int n0=nb*256+lane;
  const float4* xb=(const float4*)(x+((size_t)b*N_+n0)*128);
  float4 acc[4];
  #pragma unroll
  for(int r=0;r<4;r++) acc[r]=make_float4(0,0,0,0);
  float s1a[4]={0.f,0.f,0.f,0.f}, s2a[4]={0.f,0.f,0.f,0.f};
  bool dosum=(cgq==0)&&(w==0);
  for(int ch=0;ch<16;ch++){
    float4 wr[8];
    #pragma unroll
    for(int dd=0;dd<8;dd++) wr[dd]=w4[(ch*8+dd)*4+w];
    float4 mn0=*(const float4*)&mean[ch*8], mn1=*(const float4*)&mean[ch*8+4];
    float4 rs0=*(const float4*)&rstd[ch*8], rs1=*(const float4*)&rstd[ch*8+4];
    float4 wa0,wa1,wd0,wd1;
    if(dosum){
      wa0=*(const float4*)&wa[ch*8]; wa1=*(const float4*)&wa[ch*8+4];
      wd0=*(const float4*)&wd[ch*8]; wd1=*(const float4*)&wd[ch*8+4];
    }
    #pragma unroll
    for(int r=0;r<4;r++){
      float4 t0=xb[(size_t)r*2048+ch*2+0];
      float4 t1=xb[(size_t)r*2048+ch*2+1];
      float hv[8];
      hv[0]=(t0.x-mn0.x)*rs0.x; hv[1]=(t0.y-mn0.y)*rs0.y;
      hv[2]=(t0.z-mn0.z)*rs0.z; hv[3]=(t0.w-mn0.w)*rs0.w;
      hv[4]=(t1.x-mn1.x)*rs1.x; hv[5]=(t1.y-mn1.y)*rs1.y;
      hv[6]=(t1.z-mn1.z)*rs1.z; hv[7]=(t1.w-mn1.w)*rs1.w;
      #pragma unroll
      for(int dd=0;dd<8;dd++) fma4(acc[r],hv[dd],wr[dd]);
      if(dosum){
        s1a[r]+=hv[0]*wa0.x+hv[1]*wa0.y+hv[2]*wa0.z+hv[3]*wa0.w
               +hv[4]*wa1.x+hv[5]*wa1.y+hv[6]*wa1.z+hv[7]*wa1.w;
        s2a[r]+=hv[0]*wd0.x+hv[1]*wd0.y+hv[2]*wd0.z+hv[3]*wd0.w
               +hv[4]*wd1.x+hv[5]*wd1.y+hv[6]*wd1.z+hv[7]*wd1.w;
      }
    }
  }
  #pragma unroll
  for(int r=0;r<4;r++){
    float4* o4=(float4*)(hp+((size_t)b*N_+n0+r*64)*64+cg*4);
    o4[0]=acc[r];
  }
  if(dosum){
    #pragma unroll
    for(int r=0;r<4;r++){
      ss[(size_t)b*N_+n0+r*64]=s1a[r];
      sd[(size_t)b*N_+n0+r*64]=s2a[r];
    }
  }
}

// ---------- sort runs of 1024; 512 threads = 1 CAS/thread/pass ---------------
__global__ void __launch_bounds__(512) ksort_runs(const float* __restrict__ sdst,
                                                  unsigned long long* __restrict__ runs){
  __shared__ unsigned long long sm[1024];
  int p=blockIdx.x>>2, run=blockIdx.x&3;
  int tid=threadIdx.x;
  const float* s=sdst+(size_t)p*N_+run*1024;
  for(int l=tid;l<1024;l+=512){
    unsigned key=f2s(s[l]);
    sm[l]=((unsigned long long)key<<32)|(unsigned)(run*1024+l);
  }
  for(unsigned k=2;k<=1024u;k<<=1)
    for(unsigned j=k>>1;j>0;j>>=1){
      __syncthreads();
      unsigned t=(unsigned)tid;
      unsigned i=((t&~(j-1))<<1)|(t&(j-1));
      unsigned q=i|j;
      bool up=((i&k)==0);
      unsigned long long a=sm[i],b=sm[q];
      if((a>b)==up){sm[i]=b;sm[q]=a;}
    }
  __syncthreads();
  unsigned long long* rg=runs+(size_t)p*N_+run*1024;
  for(int l=tid;l<1024;l+=512) rg[l]=sm[l];
}

// ---------- merge 4 sorted runs by rank (binary search in LDS) ---------------
__global__ void __launch_bounds__(1024) kmerge(const unsigned long long* __restrict__ runs,
    float* __restrict__ sv, unsigned* __restrict__ perm,
    float* __restrict__ eP, float* __restrict__ eN){
  __shared__ unsigned long long sm[4096];
  int p=blockIdx.x>>2, cg=blockIdx.x&3;
  int tid=threadIdx.x;
  const unsigned long long* rg=runs+(size_t)p*N_;
  for(int l=tid;l<4096;l+=1024) sm[l]=rg[l];
  __syncthreads();
  unsigned long long e=sm[cg*1024+tid];
  int rank=tid;
  #pragma unroll
  for(int o=0;o<4;o++){
    if(o==cg) continue;
    const unsigned long long* base=sm+o*1024;
    int lo=0,hi=1024;
    while(lo<hi){int mid=(lo+hi)>>1; if(base[mid]<e) lo=mid+1; else hi=mid;}
    rank+=lo;
  }
  unsigned long long mk=sm[1023];
  if(sm[2047]>mk) mk=sm[2047];
  if(sm[3071]>mk) mk=sm[3071];
  if(sm[4095]>mk) mk=sm[4095];
  float m=s2f((unsigned)(mk>>32));
  float v=s2f((unsigned)(e>>32));
  size_t o=(size_t)p*N_+rank;
  sv[o]=v;
  perm[o]=(unsigned)(e&0xffffffffu);
  eP[o]=expf(v-m);
  eN[o]=expf(0.2f*(v-m));
}

// ---------- counts role-block: absolute scalar count prefixes for one p ------
__device__ __forceinline__ void counts_block(const float* __restrict__ eP,
    const float* __restrict__ eN, float* __restrict__ CPP, float* __restrict__ CPN,
    int p, float* s){
  int t=threadIdx.x;
  for(int pass=0;pass<2;pass++){
    const float* e=pass?eN:eP;
    float* C=pass?CPN:CPP;
    const float4* e4=(const float4*)(e+(size_t)p*N_);
    float4 a0=e4[t*4+0],a1=e4[t*4+1],a2=e4[t*4+2],a3=e4[t*4+3];
    float lp=a0.x+a0.y+a0.z+a0.w+a1.x+a1.y+a1.z+a1.w
            +a2.x+a2.y+a2.z+a2.w+a3.x+a3.y+a3.z+a3.w;
    if(pass) __syncthreads();
    s[t]=lp; __syncthreads();
    for(int off=1;off<256;off<<=1){
      float tv=(t>=off)?s[t-off]:0.f;
      __syncthreads();
      s[t]+=tv;
      __syncthreads();
    }
    float bp=s[t]-lp;
    size_t o=(size_t)p*4097+(size_t)t*16;
    C[o+ 0]=bp; bp+=a0.x; C[o+ 1]=bp; bp+=a0.y; C[o+ 2]=bp; bp+=a0.z; C[o+ 3]=bp; bp+=a0.w;
    C[o+ 4]=bp; bp+=a1.x; C[o+ 5]=bp; bp+=a1.y; C[o+ 6]=bp; bp+=a1.z; C[o+ 7]=bp; bp+=a1.w;
    C[o+ 8]=bp; bp+=a2.x; C[o+ 9]=bp; bp+=a2.y; C[o+10]=bp; bp+=a2.z; C[o+11]=bp; bp+=a2.w;
    C[o+12]=bp; bp+=a3.x; C[o+13]=bp; bp+=a3.y; C[o+14]=bp; bp+=a3.z; C[o+15]=bp;
    if(t==255) C[(size_t)p*4097+4096]=s[255];
  }
}

// ---------- layer0 tables: 8-row chunks (2 per wave) + fused counts ----------
__global__ void __launch_bounds__(256) ktables0(const unsigned* __restrict__ perm,
    const float* __restrict__ eP, const float* __restrict__ eN,
    const float* __restrict__ hp, float* __restrict__ TPP, float* __restrict__ TPN,
    float* __restrict__ rawP, float* __restrict__ rawN,
    float* __restrict__ CPP, float* __restrict__ CPN){
  __shared__ float s[256];
  if(blockIdx.x<16){ counts_block(eP,eN,CPP,CPN,blockIdx.x,s); return; }
  int gw=((blockIdx.x-16)*256+threadIdx.x)>>6;   // 0..4095
  int lane=threadIdx.x&63, half=lane>>5, ch=lane&31;
  int cglob=gw*2+half;                           // 0..8191
  int p=cglob>>9, c=cglob&511;
  float aP=0.f,aN=0.f;
  #pragma unroll
  for(int q=0;q<8;q++){
    int r=c*8+q;
    size_t ro=(size_t)p*N_+r;
    float ep=eP[ro],en=eN[ro];
    unsigned pr=perm[ro];
    float hv=hp[((size_t)p*N_+pr)*32+ch];
    size_t to=((size_t)p*4097+r)*32+ch;
    TPP[to]=aP; TPN[to]=aN;
    aP+=ep*hv; aN+=en*hv;
  }
  size_t bo=((size_t)p*512+c)*32+ch;
  rawP[bo]=aP; rawN[bo]=aN;
}

// ---------- layer1 tables: 8-row chunks (wave per chunk) + fused counts ------
__global__ void __launch_bounds__(256) ktables1(const unsigned* __restrict__ perm,
    const float* __restrict__ eP, const float* __restrict__ eN,
    const float* __restrict__ hp, float* __restrict__ TPP, float* __restrict__ TPN,
    float* __restrict__ rawP, float* __restrict__ rawN,
    float* __restrict__ CPP, float* __restrict__ CPN){
  __shared__ float s[256];
  if(blockIdx.x<4){ counts_block(eP,eN,CPP,CPN,blockIdx.x,s); return; }
  int wid=((blockIdx.x-4)*256+threadIdx.x)>>6;   // 0..2047
  int lane=threadIdx.x&63;
  int p=wid>>9, c=wid&511;
  float aP=0.f,aN=0.f;
  #pragma unroll
  for(int q=0;q<8;q++){
    int r=c*8+q;
    size_t ro=(size_t)p*N_+r;
    float ep=eP[ro],en=eN[ro];
    unsigned pr=perm[ro];
    float hv=hp[((size_t)p*N_+pr)*64+lane];
    size_t to=((size_t)p*4097+r)*64+lane;
    TPP[to]=aP; TPN[to]=aN;
    aP+=ep*hv; aN+=en*hv;
  }
  size_t bo=((size_t)p*512+c)*64+lane;
  rawP[bo]=aP; rawN[bo]=aN;
}

// ---------- scan 512 chunk sums -> bases; totals -> table row 4096 -----------
template<int D>
__global__ void __launch_bounds__(256) kscan(const float* __restrict__ rawP,
    const float* __restrict__ rawN, float* __restrict__ bP, float* __restrict__ bN,
    float* __restrict__ TPP, float* __restrict__ TPN){
  __shared__ float ssum[256];
  int p=blockIdx.x>>1, pass=blockIdx.x&1;
  const float* src=pass?rawN:rawP;
  float* dst=pass?bN:bP;
  float* tp=pass?TPN:TPP;
  int tid=threadIdx.x;
  constexpr int SEG=256/D;          // 8 (D=32) or 4 (D=64) segments
  constexpr int CPS=512/SEG;        // chunks per segment
  int ch=tid&(D-1), sg=tid/D;
  const float* s0=src+(size_t)p*512*D;
  float acc=0.f;
  for(int c=sg*CPS;c<sg*CPS+CPS;c++) acc+=s0[(size_t)c*D+ch];
  ssum[tid]=acc; __syncthreads();
  float base=0.f, tot=0.f;
  #pragma unroll
  for(int g=0;g<SEG;g++){float v=ssum[g*D+ch]; tot+=v; if(g<sg) base+=v;}
  float r=base;
  for(int c=sg*CPS;c<sg*CPS+CPS;c++){
    dst[((size_t)p*513+c)*D+ch]=r;
    r+=s0[(size_t)c*D+ch];
  }
  if(sg==0){
    dst[((size_t)p*513+512)*D+ch]=0.f;      // base for lo==4096
    tp[((size_t)p*4097+4096)*D+ch]=tot;     // absolute channel totals
  }
}

// ---------- layer0 row eval: full sv staged in padded LDS, 32 rows/block -----
// pad +1 per 128 floats: idx(j) = j + (j>>7). level1 read svl[ch*129+127] is
// conflict-free (bank = (ch+31)&31 distinct); level2 4-way; probe broadcast.
__global__ void __launch_bounds__(256) keval0(const float* __restrict__ ss,
                       const float* __restrict__ sv,
                       const float* __restrict__ bP, const float* __restrict__ bN,
                       const float* __restrict__ TPP, const float* __restrict__ TPN,
                       const float* __restrict__ CPP, const float* __restrict__ CPN,
                       const float* __restrict__ bias, float* __restrict__ out){
  __shared__ float svl[4128];   // 4096 + 32 pad
  __shared__ float ssl[32];
  int tid=threadIdx.x, blk=blockIdx.x;
  int p=blk>>7, i0=(blk&127)*32;
  int b=p>>2, h=p&3;
  const float* svp=sv+(size_t)p*N_;
  for(int j=tid;j<4096;j+=256) svl[j+(j>>7)]=svp[j];
  if(tid<32) ssl[tid]=ss[(size_t)p*N_+i0+tid];
  __syncthreads();
  int lane=tid&63, half=lane>>5, ch=lane&31;
  float bch=bias[ch];
  float m=svl[4126];            // j=4095 -> 4095+31
  float tot=TPP[((size_t)p*4097+4096)*32+ch];
  float CT =CPP[(size_t)p*4097+4096];
  for(int pass=0;pass<4;pass++){
    int rloc=pass*8+(tid>>5);
    int i=i0+rloc;
    float ssrc=ssl[rloc];
    float xx=ssrc+m;
    float M=xx>0.f?xx:0.2f*xx;
    float fpos=expf(xx-M),fneg=expf(0.2f*xx-M);
    float th=-ssrc;
    float s1v=svl[ch*129+127];
    unsigned long long bal=__ballot(s1v<=th);
    int c1=half?(int)__popcll(bal>>32):(int)__popcll(bal&0xFFFFFFFFull);
    int lo;
    if(c1>=32){ lo=4096; }
    else{
      float s2v=svl[c1*129+ch*4+3];
      unsigned long long bal2=__ballot(s2v<=th);
      int c2=half?(int)__popcll(bal2>>32):(int)__popcll(bal2&0xFFFFFFFFull);
      int base=c1*128+c2*4;
      int bi=base+c1;           // padded index of base (base>>7 == c1)
      float q0=svl[bi],q1=svl[bi+1],q2=svl[bi+2],q3=svl[bi+3];
      int c3=(q0<=th)+(q1<=th)+(q2<=th)+(q3<=th);
      lo=base+c3;
    }
    int c=lo>>3;
    float relP=TPP[((size_t)p*4097+lo)*32+ch];
    float relN=TPN[((size_t)p*4097+lo)*32+ch];
    float baP=bP[((size_t)p*513+c)*32+ch];
    float baN=bN[((size_t)p*513+c)*32+ch];
    float CPl=CPP[(size_t)p*4097+lo];
    float CNl=CPN[(size_t)p*4097+lo];
    float denom=fpos*(CT-CPl)+fneg*CNl;
    float v=fpos*(tot-(baP+relP))+fneg*(baN+relN);
    float r=v/denom+bch;
    r=r>0.f?r:expm1f(r);
    out[((size_t)(b*N_+i))*128+h*32+ch]=r;
  }
}

// ---------- layer1 row eval: full sv staged in padded LDS, 32 rows/block -----
// pad +1 per 64 floats: idx(j) = j + (j>>6). level1 svl[lane*65+63] and
// level2 svl[c1*65+lane] both 2-way (free).
__global__ void __launch_bounds__(256) keval1(const float* __restrict__ ss,
                       const float* __restrict__ sv,
                       const float* __restrict__ bP, const float* __restrict__ bN,
                       const float* __restrict__ TPP, const float* __restrict__ TPN,
                       const float* __restrict__ CPP, const float* __restrict__ CPN,
                       const float* __restrict__ bias, float* __restrict__ out){
  __shared__ float svl[4160];   // 4096 + 64 pad
  __shared__ float ssl[32];
  int tid=threadIdx.x, blk=blockIdx.x;
  int p=blk>>7, i0=(blk&127)*32;
  const float* svp=sv+(size_t)p*N_;
  for(int j=tid;j<4096;j+=256) svl[j+(j>>6)]=svp[j];
  if(tid<32) ssl[tid]=ss[(size_t)p*N_+i0+tid];
  __syncthreads();
  int lane=tid&63;
  float bch=bias[lane];
  float m=svl[4158];            // j=4095 -> 4095+63
  float tot=TPP[((size_t)p*4097+4096)*64+lane];
  float CT =CPP[(size_t)p*4097+4096];
  for(int pass=0;pass<8;pass++){
    int rloc=pass*4+(tid>>6);
    int i=i0+rloc;
    float ssrc=ssl[rloc];
    float xx=ssrc+m;
    float M=xx>0.f?xx:0.2f*xx;
    float fpos=expf(xx-M),fneg=expf(0.2f*xx-M);
    float th=-ssrc;
    float s1v=svl[lane*65+63];
    int c1=(int)__popcll(__ballot(s1v<=th));
    int lo;
    if(c1>=64){ lo=4096; }
    else{
      float s2v=svl[c1*65+lane];
      lo=c1*64+(int)__popcll(__ballot(s2v<=th));
    }
    int c=lo>>3;
    float relP=TPP[((size_t)p*4097+lo)*64+lane];
    float relN=TPN[((size_t)p*4097+lo)*64+lane];
    float baP=bP[((size_t)p*513+c)*64+lane];
    float baN=bN[((size_t)p*513+c)*64+lane];
    float CPl=CPP[(size_t)p*4097+lo];
    float CNl=CPN[(size_t)p*4097+lo];
    float denom=fpos*(CT-CPl)+fneg*CNl;
    float v=fpos*(tot-(baP+relP))+fneg*(baN+relN);
    out[((size_t)p*N_+i)*64+lane]=v/denom+bch;
  }
}

extern "C" void kernel_launch(void* const* d_in, const int* in_sizes, int n_in,
                              void* d_out, int out_size, void* d_ws, size_t ws_size,
                              hipStream_t stream) {
  const float* x  =(const float*)d_in[0];
  const float* w0 =(const float*)d_in[1];
  const float* as0=(const float*)d_in[2];
  const float* ad0=(const float*)d_in[3];
  const float* b0 =(const float*)d_in[4];
  const float* w1 =(const float*)d_in[5];
  const float* as1=(const float*)d_in[6];
  const float* ad1=(const float*)d_in[7];
  const float* b1 =(const float*)d_in[8];
  float* ws=(float*)d_ws;
  float* out=(float*)d_out;

  float* s0p = ws+OFF_S0P;
  float* s1p = ws+OFF_S1P;
  float* hp0 = ws+OFF_HP0;
  float* elu = ws+OFF_ELU;
  float* ss0 = ws+OFF_SS0;  float* sd0 = ws+OFF_SD0;
  unsigned long long* runs0=(unsigned long long*)(ws+OFF_RUNS0);
  float* sv0 = ws+OFF_SV0;
  unsigned* pm0=(unsigned*)(ws+OFF_PM0);
  float* eP0 = ws+OFF_EP0;  float* eN0 = ws+OFF_EN0;
  float* cP0 = ws+OFF_CPP0; float* cN0 = ws+OFF_CPN0;
  float* rP0 = ws+OFF_RAWP0; float* rN0 = ws+OFF_RAWN0;
  float* bP0 = ws+OFF_BP0;  float* bN0 = ws+OFF_BN0;
  float* tP0 = ws+OFF_TPP0; float* tN0 = ws+OFF_TPN0;
  float* hp1 = ws+OFF_HP1;
  float* ss1 = ws+OFF_SS1;  float* sd1 = ws+OFF_SD1;
  unsigned long long* runs1=(unsigned long long*)(ws+OFF_RUNS1);
  float* sv1 = ws+OFF_SV1;
  unsigned* pm1=(unsigned*)(ws+OFF_PM1);
  float* eP1 = ws+OFF_EP1;  float* eN1 = ws+OFF_EN1;
  float* cP1 = ws+OFF_CPP1; float* cN1 = ws+OFF_CPN1;
  float* rP1 = ws+OFF_RAWP1; float* rN1 = ws+OFF_RAWN1;
  float* bP1 = ws+OFF_BP1;  float* bN1 = ws+OFF_BN1;
  float* tP1 = ws+OFF_TPP1; float* tN1 = ws+OFF_TPN1;

  // ---- layer 0 ----
  kstats<64><<<128,256,0,stream>>>(x,s0p);
  kproj0<<<256,256,0,stream>>>(x,s0p,w0,as0,ad0,hp0,ss0,sd0);
  ksort_runs<<<64,512,0,stream>>>(sd0,runs0);
  kmerge<<<64,1024,0,stream>>>(runs0,sv0,pm0,eP0,eN0);
  ktables0<<<1040,256,0,stream>>>(pm0,eP0,eN0,hp0,tP0,tN0,rP0,rN0,cP0,cN0);
  kscan<32><<<32,256,0,stream>>>(rP0,rN0,bP0,bN0,tP0,tN0);
  keval0<<<2048,256,0,stream>>>(ss0,sv0,bP0,bN0,tP0,tN0,cP0,cN0,b0,elu);
  // ---- layer 1 ----
  kstats<128><<<128,256,0,stream>>>(elu,s1p);
  kproj1<<<256,256,0,stream>>>(elu,s1p,w1,as1,ad1,hp1,ss1,sd1);
  ksort_runs<<<16,512,0,stream>>>(sd1,runs1);
  kmerge<<<16,1024,0,stream>>>(runs1,sv1,pm1,eP1,eN1);
  ktables1<<<516,256,0,stream>>>(pm1,eP1,eN1,hp1,tP1,tN1,rP1,rN1,cP1,cN1);
  kscan<64><<<8,256,0,stream>>>(rP1,rN1,bP1,bN1,tP1,tN1);
  keval1<<<512,256,0,stream>>>(ss1,sv1,bP1,bN1,tP1,tN1,cP1,cN1,b1,out);
}